// Round 7
// baseline (113.600 us; speedup 1.0000x reference)
//
#include <hip/hip_runtime.h>
#include <math.h>

typedef unsigned short u16;
typedef __bf16 bf16x8 __attribute__((ext_vector_type(8)));
typedef float f32x4 __attribute__((ext_vector_type(4)));

#define AS1 __attribute__((address_space(1)))
#define AS3 __attribute__((address_space(3)))

#define N_    16
#define C_    512
#define HW_   1024
#define CE_   768
#define S_    77
#define NH_   8
#define D_    64
#define FEATS_ 512
#define EPS_  1e-5f
#define TOK_  (N_ * S_)   // 1232

// fp32 workspace (float offsets)
#define WS_PSTAT 0                  // 256 blocks x 2 partials
#define WS_QBIAS 1024               // 16*512
// u16 (bf16) workspace, base at byte 131072
#define WSU_BYTE 131072
#define U_OW  262144
#define U_KVW 524288
#define U_EB  1310720              // 1232*768
#define U_KVB 2256896              // 1232*1024
#define U_QT  3518464              // 16*1024*512 (ssf borrows first 64KB until mega3)
#define U_XT  11907072             // xT (raw input^T bf16), later reused as yT
#define U_QWA 20295680             // 16 x 512 x 512 per-sample scaled q weights

__device__ __forceinline__ u16 f2bf(float f) {
    unsigned u = __float_as_uint(f);
    return (u16)((u + 0x7FFFu + ((u >> 16) & 1u)) >> 16);
}

// ================= MEGA 1: stats | xT transpose | weight cvt | LN(enc) | gemv ss =================
__global__ __launch_bounds__(256) void mega1_kernel(const float* __restrict__ inp,
                                                    float* __restrict__ pstats,
                                                    u16* __restrict__ xT,
                                                    const float* __restrict__ ow,
                                                    const float* __restrict__ kvw,
                                                    u16* __restrict__ uo,
                                                    u16* __restrict__ ukv,
                                                    const float* __restrict__ enc,
                                                    const float* __restrict__ lnw,
                                                    const float* __restrict__ lnb,
                                                    u16* __restrict__ eb,
                                                    const float* __restrict__ cond,
                                                    const float* __restrict__ agw,
                                                    const float* __restrict__ agb,
                                                    float* __restrict__ ssf) {
    __shared__ __align__(16) float smem[16384];   // 64KB union for all branches
    int bid = blockIdx.x;
    int tid = threadIdx.x;
    if (bid < 256) {
        // ---- stats: per-block partial sum/sumsq ----
        int n = bid >> 4, slice = bid & 15;
        const float* base = inp + (size_t)n * C_ * HW_ + slice * (C_ * HW_ / 16);
        float s = 0.f, s2 = 0.f;
        const float4* b4 = (const float4*)base;
        for (int i = tid; i < (C_ * HW_ / 16) / 4; i += 256) {
            float4 v = b4[i];
            s  += v.x + v.y + v.z + v.w;
            s2 += v.x * v.x + v.y * v.y + v.z * v.z + v.w * v.w;
        }
        for (int off = 32; off; off >>= 1) {
            s  += __shfl_down(s, off);
            s2 += __shfl_down(s2, off);
        }
        int wid = tid >> 6, lane = tid & 63;
        if (lane == 0) { smem[wid] = s; smem[4 + wid] = s2; }
        __syncthreads();
        if (tid == 0) {
            pstats[bid * 2]     = smem[0] + smem[1] + smem[2] + smem[3];
            pstats[bid * 2 + 1] = smem[4] + smem[5] + smem[6] + smem[7];
        }
    } else if (bid < 2304) {
        // ---- xT[n][hw][c] = input[n][c][hw] (bf16, NO alpha) ----
        int bid2 = bid - 256;
        int n = bid2 >> 7, rem = bid2 & 127;
        int c0 = (rem >> 4) * 64, h0 = (rem & 15) * 64;
        float (*t)[65] = (float(*)[65])smem;      // 64x65 = 16.6KB
        int rr = tid >> 4, cc = (tid & 15) * 4;
#pragma unroll
        for (int i = 0; i < 4; i++) {
            int cl = rr + i * 16;
            int c = c0 + cl;
            float4 v = *(const float4*)(inp + ((size_t)n * C_ + c) * HW_ + h0 + cc);
            t[cl][cc + 0] = v.x; t[cl][cc + 1] = v.y;
            t[cl][cc + 2] = v.z; t[cl][cc + 3] = v.w;
        }
        __syncthreads();
#pragma unroll
        for (int i = 0; i < 4; i++) {
            int hl = rr + i * 16;
            ushort4 w;
            w.x = f2bf(t[cc + 0][hl]); w.y = f2bf(t[cc + 1][hl]);
            w.z = f2bf(t[cc + 2][hl]); w.w = f2bf(t[cc + 3][hl]);
            *(ushort4*)(xT + ((size_t)n * HW_ + h0 + hl) * C_ + c0 + cc) = w;
        }
    } else if (bid < 3328) {
        // ---- cvt2: fp32 -> bf16 weights (ow, kvw) ----
        int i = (bid - 2304) * 256 + tid;
        const float* s; u16* d; int j;
        if (i < 65536) { s = ow;  d = uo;  j = i; }
        else           { s = kvw; d = ukv; j = i - 65536; }
        float4 v = ((const float4*)s)[j];
        ushort4 w;
        w.x = f2bf(v.x); w.y = f2bf(v.y); w.z = f2bf(v.z); w.w = f2bf(v.w);
        ((ushort4*)(d))[j] = w;
    } else if (bid < 4560) {
        // ---- layernorm(enc) -> eb bf16 ----
        int tok = bid - 3328;
        const float* row = enc + (size_t)tok * CE_;
        int t = tid;
        float v0 = row[t], v1 = row[t + 256], v2 = row[t + 512];
        float sum = v0 + v1 + v2;
        float sq  = v0 * v0 + v1 * v1 + v2 * v2;
        for (int off = 32; off; off >>= 1) {
            sum += __shfl_down(sum, off);
            sq  += __shfl_down(sq, off);
        }
        int wid = t >> 6, lane = t & 63;
        if (lane == 0) { smem[wid] = sum; smem[4 + wid] = sq; }
        __syncthreads();
        float tot = smem[0] + smem[1] + smem[2] + smem[3];
        float tsq = smem[4] + smem[5] + smem[6] + smem[7];
        float mu  = tot / CE_;
        float var = tsq / CE_ - mu * mu;
        float rstd = rsqrtf(var + EPS_);
        u16* o = eb + (size_t)tok * CE_;
        o[t]       = f2bf((v0 - mu) * rstd * lnw[t] + lnb[t]);
        o[t + 256] = f2bf((v1 - mu) * rstd * lnw[t + 256] + lnb[t + 256]);
        o[t + 512] = f2bf((v2 - mu) * rstd * lnw[t + 512] + lnb[t + 512]);
    } else {
        // ---- gemv_ss: ssf[n][r] = agb[r] + dot(cond[n], agw[r]) ----
        float (*wz)[512] = (float(*)[512])smem;
        float (*cz)[512] = (float(*)[512])(smem + 8192);
        int r0 = (bid - 4560) * 16;
        for (int i = tid; i < 2048; i += 256) {
            int row = i >> 7, f4 = i & 127;
            *(float4*)&cz[row][f4 * 4] = ((const float4*)(cond + (size_t)row * 512))[f4];
            *(float4*)&wz[row][f4 * 4] = ((const float4*)(agw + (size_t)(r0 + row) * 512))[f4];
        }
        __syncthreads();
        int n = tid >> 4, r = tid & 15;
        float acc = agb[r0 + r];
        for (int i = 0; i < 128; i++) {
            int j = (r + i) & 127;
            float4 c4 = *(const float4*)&cz[n][j * 4];
            float4 w4 = *(const float4*)&wz[r][j * 4];
            acc += c4.x * w4.x + c4.y * w4.y + c4.z * w4.z + c4.w * w4.w;
        }
        ssf[(size_t)n * 1024 + r0 + r] = acc;
    }
}

// ================= MEGA 2: qwa = qw * alpha[n]  |  qbias gemv (beta inline) =================
__global__ __launch_bounds__(256) void mega2_kernel(const float* __restrict__ ssf,
                                                    const float* __restrict__ pstats,
                                                    const float* __restrict__ qw,
                                                    u16* __restrict__ qwa,
                                                    const float* __restrict__ qb,
                                                    float* __restrict__ qbias) {
    __shared__ __align__(16) float smem[16384];
    __shared__ float muS[16], rsS[16];
    int bid = blockIdx.x;
    int tid = threadIdx.x;
    float cnt = (float)(C_ * HW_);
    if (bid < 256) {
        // ---- qwa[n][o0+o][c] = qw[o0+o][c] * alpha[n][c] ----
        int n = bid >> 4, o0 = (bid & 15) * 32;
        float s = 0.f, s2 = 0.f;
        for (int k = 0; k < 16; k++) {
            s  += pstats[(n * 16 + k) * 2];
            s2 += pstats[(n * 16 + k) * 2 + 1];
        }
        float mu = s / cnt;
        float rstd = rsqrtf(s2 / cnt - mu * mu + EPS_);
        float* al = smem;                           // 512 floats
        for (int c = tid; c < 512; c += 256)
            al[c] = rstd * (ssf[(size_t)n * 1024 + c] + 1.f);
        __syncthreads();
        u16* dst = qwa + (size_t)n * 262144;
        for (int i = tid; i < 4096; i += 256) {     // 32 rows x 128 float4
            int o = i >> 7, f4 = i & 127;
            float4 w4 = ((const float4*)(qw + (size_t)(o0 + o) * 512))[f4];
            int c = f4 * 4;
            ushort4 w;
            w.x = f2bf(w4.x * al[c]);     w.y = f2bf(w4.y * al[c + 1]);
            w.z = f2bf(w4.z * al[c + 2]); w.w = f2bf(w4.w * al[c + 3]);
            *(ushort4*)(dst + (size_t)(o0 + o) * 512 + c) = w;
        }
    } else {
        // ---- qbias[n][r] = qb[r] + dot(beta[n], qw[r]); beta inline ----
        float (*wz)[512] = (float(*)[512])smem;
        float (*cz)[512] = (float(*)[512])(smem + 8192);
        int r0 = (bid - 256) * 16;
        if (tid < 16) {
            float s = 0.f, s2 = 0.f;
            for (int k = 0; k < 16; k++) {
                s  += pstats[(tid * 16 + k) * 2];
                s2 += pstats[(tid * 16 + k) * 2 + 1];
            }
            float mu = s / cnt;
            muS[tid] = mu;
            rsS[tid] = rsqrtf(s2 / cnt - mu * mu + EPS_);
        }
        __syncthreads();
        for (int i = tid; i < 2048; i += 256) {
            int row = i >> 7, f4 = i & 127;
            float4 sc4 = ((const float4*)(ssf + (size_t)row * 1024))[f4];
            float4 sh4 = ((const float4*)(ssf + (size_t)row * 1024 + 512))[f4];
            float mu = muS[row], rs = rsS[row];
            float4 b;
            b.x = sh4.x - mu * (rs * (sc4.x + 1.f));
            b.y = sh4.y - mu * (rs * (sc4.y + 1.f));
            b.z = sh4.z - mu * (rs * (sc4.z + 1.f));
            b.w = sh4.w - mu * (rs * (sc4.w + 1.f));
            *(float4*)&cz[row][f4 * 4] = b;
            *(float4*)&wz[row][f4 * 4] = ((const float4*)(qw + (size_t)(r0 + row) * 512))[f4];
        }
        __syncthreads();
        int n = tid >> 4, r = tid & 15;
        float acc = qb[r0 + r];
        for (int i = 0; i < 128; i++) {
            int j = (r + i) & 127;
            float4 c4 = *(const float4*)&cz[n][j * 4];
            float4 w4 = *(const float4*)&wz[r][j * 4];
            acc += c4.x * w4.x + c4.y * w4.y + c4.z * w4.z + c4.w * w4.w;
        }
        qbias[(size_t)n * 512 + r0 + r] = acc;
    }
}

// ---------------- MFMA GEMM mainloop ----------------
__device__ __forceinline__ void gemm_mainloop(const u16* __restrict__ A, int lda, int arow0,
                                              const u16* __restrict__ B, int ldb, int brow0, int brmax,
                                              int K, f32x4 (&acc)[4][4], u16* As, u16* Bs) {
    int tid = threadIdx.x;
    int lane = tid & 63;
    int wm = ((tid >> 6) >> 1) * 64, wn = ((tid >> 6) & 1) * 64;
    int srow = tid >> 3;
    int sw = (tid & 7) ^ (srow & 7);
    int ldsoff = tid * 8;
    for (int kt = 0; kt < K; kt += 64) {
        __syncthreads();
#pragma unroll
        for (int i = 0; i < 4; i++) {
            int ar = arow0 + i * 32 + srow;
            const u16* ga = A + (size_t)ar * lda + kt + sw * 8;
            __builtin_amdgcn_global_load_lds((AS1 void*)ga, (AS3 void*)(As + i * 2048 + ldsoff), 16, 0, 0);
            int br = brow0 + i * 32 + srow; if (br > brmax) br = brmax;
            const u16* gb = B + (size_t)br * ldb + kt + sw * 8;
            __builtin_amdgcn_global_load_lds((AS1 void*)gb, (AS3 void*)(Bs + i * 2048 + ldsoff), 16, 0, 0);
        }
        __syncthreads();
#pragma unroll
        for (int kk = 0; kk < 2; kk++) {
            bf16x8 af[4], bfv[4];
            int ks = kk * 4 + (lane >> 4);
#pragma unroll
            for (int mi = 0; mi < 4; mi++) {
                int r = wm + mi * 16 + (lane & 15);
                af[mi] = *(const bf16x8*)(As + r * 64 + (ks ^ (r & 7)) * 8);
            }
#pragma unroll
            for (int ni = 0; ni < 4; ni++) {
                int r = wn + ni * 16 + (lane & 15);
                bfv[ni] = *(const bf16x8*)(Bs + r * 64 + (ks ^ (r & 7)) * 8);
            }
#pragma unroll
            for (int mi = 0; mi < 4; mi++)
#pragma unroll
                for (int ni = 0; ni < 4; ni++)
                    acc[mi][ni] = __builtin_amdgcn_mfma_f32_16x16x32_bf16(af[mi], bfv[ni], acc[mi][ni], 0, 0, 0);
        }
    }
}

// ================= MEGA 3: Q GEMM (512 blocks, per-n qwa) | KV GEMM (80 blocks) =================
__global__ __launch_bounds__(256) void mega3_kernel(const u16* __restrict__ qwa,
                                                    const u16* __restrict__ xT,
                                                    const float* __restrict__ qbias,
                                                    u16* __restrict__ qt,
                                                    const u16* __restrict__ kvwb,
                                                    const u16* __restrict__ eb,
                                                    const float* __restrict__ kvbias,
                                                    u16* __restrict__ kvo) {
    __shared__ __align__(16) u16 As[128 * 64];
    __shared__ __align__(16) u16 Bs[128 * 64];
    int bid = blockIdx.x;
    int lane = threadIdx.x & 63, wid = threadIdx.x >> 6;
    int wm = (wid >> 1) * 64, wn = (wid & 1) * 64;
    f32x4 acc[4][4];
#pragma unroll
    for (int mi = 0; mi < 4; mi++)
#pragma unroll
        for (int ni = 0; ni < 4; ni++) acc[mi][ni] = 0.f;

    if (bid < 512) {
        int n = bid >> 5, r = bid & 31;
        int brow0 = (r & 7) * 128, arow0 = (r >> 3) * 128;
        gemm_mainloop(qwa + (size_t)n * 262144, C_, arow0,
                      xT + (size_t)n * HW_ * C_, C_, brow0, HW_ - 1, C_, acc, As, Bs);
        u16* CT = qt + (size_t)n * HW_ * C_;
        const float* qbn = qbias + n * C_;
#pragma unroll
        for (int mi = 0; mi < 4; mi++) {
            int row = arow0 + wm + mi * 16 + ((lane >> 4) << 2);
            float4 b4 = *(const float4*)(qbn + row);
#pragma unroll
            for (int ni = 0; ni < 4; ni++) {
                int col = brow0 + wn + ni * 16 + (lane & 15);
                f32x4 v = acc[mi][ni];
                ushort4 w;
                w.x = f2bf(v.x + b4.x); w.y = f2bf(v.y + b4.y);
                w.z = f2bf(v.z + b4.z); w.w = f2bf(v.w + b4.w);
                *(ushort4*)(CT + (size_t)col * C_ + row) = w;
            }
        }
    } else {
        int t = bid - 512;
        int brow0 = (t % 10) * 128, arow0 = (t / 10) * 128;
        gemm_mainloop(kvwb, CE_, arow0, eb, CE_, brow0, TOK_ - 1, CE_, acc, As, Bs);
#pragma unroll
        for (int mi = 0; mi < 4; mi++) {
            int row = arow0 + wm + mi * 16 + ((lane >> 4) << 2);
            float4 b4 = *(const float4*)(kvbias + row);
#pragma unroll
            for (int ni = 0; ni < 4; ni++) {
                int col = brow0 + wn + ni * 16 + (lane & 15);
                if (col < TOK_) {
                    f32x4 v = acc[mi][ni];
                    ushort4 w;
                    w.x = f2bf(v.x + b4.x); w.y = f2bf(v.y + b4.y);
                    w.z = f2bf(v.z + b4.z); w.w = f2bf(v.w + b4.w);
                    *(ushort4*)(kvo + (size_t)col * 1024 + row) = w;
                }
            }
        }
    }
}

// ---------------- OUT GEMM: out[n][o][hw] = acc + ob[o] + input, fp32 ----------------
__global__ __launch_bounds__(256) void gemm_out_mfma(const u16* __restrict__ owb,
                                                     const u16* __restrict__ yT,
                                                     const float* __restrict__ ob,
                                                     const float* __restrict__ inp,
                                                     float* __restrict__ outp) {
    __shared__ __align__(16) u16 As[128 * 64];
    __shared__ __align__(16) u16 Bs[128 * 64];
    int n = blockIdx.z;
    int arow0 = blockIdx.y * 128, brow0 = blockIdx.x * 128;
    f32x4 acc[4][4];
#pragma unroll
    for (int mi = 0; mi < 4; mi++)
#pragma unroll
        for (int ni = 0; ni < 4; ni++) acc[mi][ni] = 0.f;
    gemm_mainloop(owb, C_, arow0, yT + (size_t)n * HW_ * C_, C_, brow0, HW_ - 1, C_, acc, As, Bs);
    int lane = threadIdx.x & 63, wid = threadIdx.x >> 6;
    int wm = (wid >> 1) * 64, wn = (wid & 1) * 64;
    float* Co = outp + (size_t)n * C_ * HW_;
    const float* In = inp + (size_t)n * C_ * HW_;
#pragma unroll
    for (int mi = 0; mi < 4; mi++) {
        int row = arow0 + wm + mi * 16 + ((lane >> 4) << 2);
        float4 b4 = *(const float4*)(ob + row);
#pragma unroll
        for (int ni = 0; ni < 4; ni++) {
            int col = brow0 + wn + ni * 16 + (lane & 15);
            f32x4 v = acc[mi][ni];
            size_t i0 = (size_t)row * HW_ + col;
            Co[i0]            = v.x + b4.x + In[i0];
            Co[i0 + HW_]      = v.y + b4.y + In[i0 + HW_];
            Co[i0 + 2 * HW_]  = v.z + b4.z + In[i0 + 2 * HW_];
            Co[i0 + 3 * HW_]  = v.w + b4.w + In[i0 + 3 * HW_];
        }
    }
}

// ---------------- MFMA attention (swapped-operand): 64 q-rows / block, 4 waves ----------------
__global__ __launch_bounds__(256) void attn_mfma(const u16* __restrict__ kvb,
                                                 const float* __restrict__ mask,
                                                 const u16* __restrict__ qt,
                                                 u16* __restrict__ yt) {
    int nh = blockIdx.x;
    int n = nh >> 3, h = nh & 7;
    int qb = blockIdx.y;
    __shared__ __align__(16) u16 Qs[64 * 64];
    __shared__ __align__(16) u16 Ks[80 * 64];
    __shared__ __align__(16) u16 VT[64 * 104];
    __shared__ __align__(16) u16 Ps[64 * 104];
    __shared__ float msk[80];
    int tid = threadIdx.x;
    int lane = tid & 63, w = tid >> 6;
    int g = lane >> 4, l15 = lane & 15;

    const u16* qbase = qt + ((size_t)(n * HW_ + qb * 64)) * C_ + h * 64;
#pragma unroll
    for (int pass = 0; pass < 2; pass++) {
        int idx = pass * 256 + tid;
        int row = idx >> 3, slot = idx & 7;
        int sw = slot ^ (row & 7);
        __builtin_amdgcn_global_load_lds((AS1 void*)(qbase + (size_t)row * C_ + sw * 8),
                                         (AS3 void*)(Qs + idx * 8), 16, 0, 0);
    }
    const u16* kbase = kvb + (size_t)(n * S_) * 1024 + h * 64;
#pragma unroll
    for (int pass = 0; pass < 3; pass++) {
        int idx = pass * 256 + tid;
        if (idx < 640) {
            int row = idx >> 3, slot = idx & 7;
            int srow = row < S_ ? row : S_ - 1;
            int sw = slot ^ (row & 7);
            __builtin_amdgcn_global_load_lds((AS1 void*)(kbase + (size_t)srow * 1024 + sw * 8),
                                             (AS3 void*)(Ks + idx * 8), 16, 0, 0);
        }
    }
    {
        int d = tid & 63, sg = tid >> 6;
        const u16* vbase = kvb + (size_t)(n * S_) * 1024 + 512 + h * 64 + d;
        for (int s = sg; s < 104; s += 4) {
            u16 v = (s < S_) ? vbase[(size_t)s * 1024] : (u16)0;
            VT[d * 104 + s] = v;
        }
    }
    for (int i = tid; i < 512; i += 256) {
        int r = i >> 3, cp = i & 7;
        *(unsigned*)&Ps[r * 104 + 80 + cp * 2] = 0u;
    }
    if (tid < 80) msk[tid] = (tid < S_) ? mask[n * S_ + tid] * 10000.f : 0.f;
    __syncthreads();

    int qrow = w * 16 + l15;

    bf16x8 qf[2];
#pragma unroll
    for (int kk = 0; kk < 2; kk++) {
        int s8 = kk * 4 + g;
        qf[kk] = *(const bf16x8*)(Qs + qrow * 64 + (s8 ^ (qrow & 7)) * 8);
    }
    f32x4 sc[5];
#pragma unroll
    for (int kb = 0; kb < 5; kb++) {
        sc[kb] = 0.f;
#pragma unroll
        for (int kk = 0; kk < 2; kk++) {
            int r = kb * 16 + l15;
            int s8 = kk * 4 + g;
            bf16x8 kf = *(const bf16x8*)(Ks + r * 64 + (s8 ^ (r & 7)) * 8);
            sc[kb] = __builtin_amdgcn_mfma_f32_16x16x32_bf16(kf, qf[kk], sc[kb], 0, 0, 0);
        }
    }
    float sv[5][4];
    float mx = -3e38f;
#pragma unroll
    for (int kb = 0; kb < 5; kb++)
#pragma unroll
        for (int j = 0; j < 4; j++) {
            int key = kb * 16 + g * 4 + j;
            float s = sc[kb][j] * 0.125f - msk[key];
            sv[kb][j] = s;
            if (key < S_) mx = fmaxf(mx, s);
        }
    mx = fmaxf(mx, __shfl_xor(mx, 16));
    mx = fmaxf(mx, __shfl_xor(mx, 32));
    float sum = 0.f;
    float p[5][4];
#pragma unroll
    for (int kb = 0; kb < 5; kb++)
#pragma unroll
        for (int j = 0; j < 4; j++) {
            int key = kb * 16 + g * 4 + j;
            float pv = (key < S_) ? __expf(sv[kb][j] - mx) : 0.f;
            p[kb][j] = pv;
            sum += pv;
        }
    sum += __shfl_xor(sum, 16);
    sum += __shfl_xor(sum, 32);
    float inv = 1.f / sum;
#pragma unroll
    for (int kb = 0; kb < 5; kb++) {
        unsigned lo = (unsigned)f2bf(p[kb][0] * inv) | ((unsigned)f2bf(p[kb][1] * inv) << 16);
        unsigned hi = (unsigned)f2bf(p[kb][2] * inv) | ((unsigned)f2bf(p[kb][3] * inv) << 16);
        int col = kb * 16 + g * 4;
        *(uint2*)&Ps[qrow * 104 + col] = make_uint2(lo, hi);
    }
    f32x4 ya[4];
#pragma unroll
    for (int mf = 0; mf < 4; mf++) ya[mf] = 0.f;
#pragma unroll
    for (int kk = 0; kk < 3; kk++) {
        int s8 = kk * 4 + g;
        bf16x8 pf = *(const bf16x8*)(Ps + qrow * 104 + s8 * 8);
#pragma unroll
        for (int mf = 0; mf < 4; mf++) {
            bf16x8 vf = *(const bf16x8*)(VT + (mf * 16 + l15) * 104 + s8 * 8);
            ya[mf] = __builtin_amdgcn_mfma_f32_16x16x32_bf16(vf, pf, ya[mf], 0, 0, 0);
        }
    }
    u16* yrow = yt + ((size_t)(n * HW_ + qb * 64 + qrow)) * C_ + h * 64;
#pragma unroll
    for (int mf = 0; mf < 4; mf++) {
        int d0 = mf * 16 + g * 4;
        ushort4 o;
        o.x = f2bf(ya[mf][0]); o.y = f2bf(ya[mf][1]);
        o.z = f2bf(ya[mf][2]); o.w = f2bf(ya[mf][3]);
        *(ushort4*)(yrow + d0) = o;
    }
}

extern "C" void kernel_launch(void* const* d_in, const int* in_sizes, int n_in,
                              void* d_out, int out_size, void* d_ws, size_t ws_size,
                              hipStream_t stream) {
    const float* inp  = (const float*)d_in[0];
    const float* cond = (const float*)d_in[1];
    const float* enc  = (const float*)d_in[2];
    const float* mask = (const float*)d_in[3];
    const float* agw  = (const float*)d_in[4];
    const float* agb  = (const float*)d_in[5];
    const float* lnw  = (const float*)d_in[6];
    const float* lnb  = (const float*)d_in[7];
    const float* qw   = (const float*)d_in[8];
    const float* qb   = (const float*)d_in[9];
    const float* kvw  = (const float*)d_in[10];
    const float* kvb  = (const float*)d_in[11];
    const float* ow   = (const float*)d_in[12];
    const float* ob   = (const float*)d_in[13];
    float* ws  = (float*)d_ws;
    float* out = (float*)d_out;
    u16* wsu = (u16*)((char*)d_ws + WSU_BYTE);
    float* ssf = (float*)(wsu + U_QT);     // 16x1024 fp32, consumed before mega3 writes qt

    // mega1: stats(256) | xT(2048) | cvt2(1024) | ln(1232) | gemv_ss(64) = 4624 blocks
    mega1_kernel<<<dim3(4624), 256, 0, stream>>>(inp, ws + WS_PSTAT, wsu + U_XT,
                                                 ow, kvw, wsu + U_OW, wsu + U_KVW,
                                                 enc, lnw, lnb, wsu + U_EB,
                                                 cond, agw, agb, ssf);
    // mega2: qwa(256) | qbias(32) = 288 blocks
    mega2_kernel<<<dim3(288), 256, 0, stream>>>(ssf, ws + WS_PSTAT, qw,
                                                wsu + U_QWA, qb, ws + WS_QBIAS);
    // mega3: gemm_q(512) | gemm_kv(80) = 592 blocks
    mega3_kernel<<<dim3(592), 256, 0, stream>>>(wsu + U_QWA, wsu + U_XT, ws + WS_QBIAS, wsu + U_QT,
                                                wsu + U_KVW, wsu + U_EB, kvb, wsu + U_KVB);

    attn_mfma<<<dim3(N_ * NH_, HW_ / 64), 256, 0, stream>>>(
        wsu + U_KVB, mask, wsu + U_QT, wsu + U_XT);   // yT aliases xT (consumed)

    gemm_out_mfma<<<dim3(HW_ / 128, C_ / 128, N_), 256, 0, stream>>>(
        wsu + U_OW, wsu + U_XT, ob, inp, out);
}

// Round 8
// 102.049 us; speedup vs baseline: 1.1132x; 1.1132x over previous
//
#include <hip/hip_runtime.h>
#include <math.h>

typedef unsigned short u16;
typedef __bf16 bf16x8 __attribute__((ext_vector_type(8)));
typedef float f32x4 __attribute__((ext_vector_type(4)));

#define AS1 __attribute__((address_space(1)))
#define AS3 __attribute__((address_space(3)))

#define N_    16
#define C_    512
#define HW_   1024
#define CE_   768
#define S_    77
#define NH_   8
#define D_    64
#define FEATS_ 512
#define EPS_  1e-5f
#define TOK_  (N_ * S_)   // 1232

// fp32 workspace (float offsets)
#define WS_PSTAT 0                  // 256 blocks x 2 partials
#define WS_QBIAS 1024               // 16*512
// u16 (bf16) workspace, base at byte 131072
#define WSU_BYTE 131072
#define U_QW  0
#define U_OW  262144
#define U_KVW 524288
#define U_EB  1310720              // 1232*768
#define U_KVB 2256896              // 1232*1024
#define U_QT  3518464              // 16*1024*512 (ssf borrows first 64KB until mega3)
#define U_XT  11907072             // xT (alpha folded), later reused as yT

__device__ __forceinline__ u16 f2bf(float f) {
    unsigned u = __float_as_uint(f);
    return (u16)((u + 0x7FFFu + ((u >> 16) & 1u)) >> 16);
}

// ================= MEGA 1: stats partials | weight cvt | LN(enc) | gemv ss =================
__global__ __launch_bounds__(256) void mega1_kernel(const float* __restrict__ inp,
                                                    float* __restrict__ pstats,
                                                    const float* __restrict__ qw,
                                                    const float* __restrict__ ow,
                                                    const float* __restrict__ kvw,
                                                    u16* __restrict__ uq,
                                                    u16* __restrict__ uo,
                                                    u16* __restrict__ ukv,
                                                    const float* __restrict__ enc,
                                                    const float* __restrict__ lnw,
                                                    const float* __restrict__ lnb,
                                                    u16* __restrict__ eb,
                                                    const float* __restrict__ cond,
                                                    const float* __restrict__ agw,
                                                    const float* __restrict__ agb,
                                                    float* __restrict__ ssf) {
    __shared__ __align__(16) float smem[16384];   // 64KB union
    int bid = blockIdx.x;
    int tid = threadIdx.x;
    if (bid < 256) {
        int n = bid >> 4, slice = bid & 15;
        const float* base = inp + (size_t)n * C_ * HW_ + slice * (C_ * HW_ / 16);
        float s = 0.f, s2 = 0.f;
        const float4* b4 = (const float4*)base;
        for (int i = tid; i < (C_ * HW_ / 16) / 4; i += 256) {
            float4 v = b4[i];
            s  += v.x + v.y + v.z + v.w;
            s2 += v.x * v.x + v.y * v.y + v.z * v.z + v.w * v.w;
        }
        for (int off = 32; off; off >>= 1) {
            s  += __shfl_down(s, off);
            s2 += __shfl_down(s2, off);
        }
        int wid = tid >> 6, lane = tid & 63;
        if (lane == 0) { smem[wid] = s; smem[4 + wid] = s2; }
        __syncthreads();
        if (tid == 0) {
            pstats[bid * 2]     = smem[0] + smem[1] + smem[2] + smem[3];
            pstats[bid * 2 + 1] = smem[4] + smem[5] + smem[6] + smem[7];
        }
    } else if (bid < 1536) {
        int i = (bid - 256) * 256 + tid;
        const float* s; u16* d; int j;
        if (i < 65536)       { s = qw;  d = uq;  j = i; }
        else if (i < 131072) { s = ow;  d = uo;  j = i - 65536; }
        else                 { s = kvw; d = ukv; j = i - 131072; }
        float4 v = ((const float4*)s)[j];
        ushort4 w;
        w.x = f2bf(v.x); w.y = f2bf(v.y); w.z = f2bf(v.z); w.w = f2bf(v.w);
        ((ushort4*)(d))[j] = w;
    } else if (bid < 2768) {
        int tok = bid - 1536;
        const float* row = enc + (size_t)tok * CE_;
        int t = tid;
        float v0 = row[t], v1 = row[t + 256], v2 = row[t + 512];
        float sum = v0 + v1 + v2;
        float sq  = v0 * v0 + v1 * v1 + v2 * v2;
        for (int off = 32; off; off >>= 1) {
            sum += __shfl_down(sum, off);
            sq  += __shfl_down(sq, off);
        }
        int wid = t >> 6, lane = t & 63;
        if (lane == 0) { smem[wid] = sum; smem[4 + wid] = sq; }
        __syncthreads();
        float tot = smem[0] + smem[1] + smem[2] + smem[3];
        float tsq = smem[4] + smem[5] + smem[6] + smem[7];
        float mu  = tot / CE_;
        float var = tsq / CE_ - mu * mu;
        float rstd = rsqrtf(var + EPS_);
        u16* o = eb + (size_t)tok * CE_;
        o[t]       = f2bf((v0 - mu) * rstd * lnw[t] + lnb[t]);
        o[t + 256] = f2bf((v1 - mu) * rstd * lnw[t + 256] + lnb[t + 256]);
        o[t + 512] = f2bf((v2 - mu) * rstd * lnw[t + 512] + lnb[t + 512]);
    } else {
        float (*wz)[512] = (float(*)[512])smem;
        float (*cz)[512] = (float(*)[512])(smem + 8192);
        int r0 = (bid - 2768) * 16;
        for (int i = tid; i < 2048; i += 256) {
            int row = i >> 7, f4 = i & 127;
            *(float4*)&cz[row][f4 * 4] = ((const float4*)(cond + (size_t)row * 512))[f4];
            *(float4*)&wz[row][f4 * 4] = ((const float4*)(agw + (size_t)(r0 + row) * 512))[f4];
        }
        __syncthreads();
        int n = tid >> 4, r = tid & 15;
        float acc = agb[r0 + r];
        for (int i = 0; i < 128; i++) {
            int j = (r + i) & 127;
            float4 c4 = *(const float4*)&cz[n][j * 4];
            float4 w4 = *(const float4*)&wz[r][j * 4];
            acc += c4.x * w4.x + c4.y * w4.y + c4.z * w4.z + c4.w * w4.w;
        }
        ssf[(size_t)n * 1024 + r0 + r] = acc;
    }
}

// ================= MEGA 2: xT (alpha inline) | gemv qbias (beta inline) =================
__global__ __launch_bounds__(256) void mega2_kernel(const float* __restrict__ inp,
                                                    const float* __restrict__ ssf,
                                                    const float* __restrict__ pstats,
                                                    u16* __restrict__ xT,
                                                    const float* __restrict__ qw,
                                                    const float* __restrict__ qb,
                                                    float* __restrict__ qbias) {
    __shared__ __align__(16) float smem[16384];
    __shared__ float muS[16], rsS[16];
    int bid = blockIdx.x;
    int tid = threadIdx.x;
    float cnt = (float)(C_ * HW_);
    if (bid < 2048) {
        int n = bid >> 7, rem = bid & 127;
        int c0 = (rem >> 4) * 64, h0 = (rem & 15) * 64;
        float s = 0.f, s2 = 0.f;
        for (int k = 0; k < 16; k++) {
            s  += pstats[(n * 16 + k) * 2];
            s2 += pstats[(n * 16 + k) * 2 + 1];
        }
        float mu = s / cnt;
        float rstd = rsqrtf(s2 / cnt - mu * mu + EPS_);
        float (*t)[65] = (float(*)[65])smem;
        int rr = tid >> 4, cc = (tid & 15) * 4;
#pragma unroll
        for (int i = 0; i < 4; i++) {
            int cl = rr + i * 16;
            int c = c0 + cl;
            float a = rstd * (ssf[(size_t)n * 1024 + c] + 1.f);
            float4 v = *(const float4*)(inp + ((size_t)n * C_ + c) * HW_ + h0 + cc);
            t[cl][cc + 0] = v.x * a; t[cl][cc + 1] = v.y * a;
            t[cl][cc + 2] = v.z * a; t[cl][cc + 3] = v.w * a;
        }
        __syncthreads();
#pragma unroll
        for (int i = 0; i < 4; i++) {
            int hl = rr + i * 16;
            ushort4 w;
            w.x = f2bf(t[cc + 0][hl]); w.y = f2bf(t[cc + 1][hl]);
            w.z = f2bf(t[cc + 2][hl]); w.w = f2bf(t[cc + 3][hl]);
            *(ushort4*)(xT + ((size_t)n * HW_ + h0 + hl) * C_ + c0 + cc) = w;
        }
    } else {
        float (*wz)[512] = (float(*)[512])smem;
        float (*cz)[512] = (float(*)[512])(smem + 8192);
        int r0 = (bid - 2048) * 16;
        if (tid < 16) {
            float s = 0.f, s2 = 0.f;
            for (int k = 0; k < 16; k++) {
                s  += pstats[(tid * 16 + k) * 2];
                s2 += pstats[(tid * 16 + k) * 2 + 1];
            }
            float mu = s / cnt;
            muS[tid] = mu;
            rsS[tid] = rsqrtf(s2 / cnt - mu * mu + EPS_);
        }
        __syncthreads();
        for (int i = tid; i < 2048; i += 256) {
            int row = i >> 7, f4 = i & 127;
            float4 sc4 = ((const float4*)(ssf + (size_t)row * 1024))[f4];
            float4 sh4 = ((const float4*)(ssf + (size_t)row * 1024 + 512))[f4];
            float mu = muS[row], rs = rsS[row];
            float4 b;
            b.x = sh4.x - mu * (rs * (sc4.x + 1.f));
            b.y = sh4.y - mu * (rs * (sc4.y + 1.f));
            b.z = sh4.z - mu * (rs * (sc4.z + 1.f));
            b.w = sh4.w - mu * (rs * (sc4.w + 1.f));
            *(float4*)&cz[row][f4 * 4] = b;
            *(float4*)&wz[row][f4 * 4] = ((const float4*)(qw + (size_t)(r0 + row) * 512))[f4];
        }
        __syncthreads();
        int n = tid >> 4, r = tid & 15;
        float acc = qb[r0 + r];
        for (int i = 0; i < 128; i++) {
            int j = (r + i) & 127;
            float4 c4 = *(const float4*)&cz[n][j * 4];
            float4 w4 = *(const float4*)&wz[r][j * 4];
            acc += c4.x * w4.x + c4.y * w4.y + c4.z * w4.z + c4.w * w4.w;
        }
        qbias[(size_t)n * 512 + r0 + r] = acc;
    }
}

// ---------------- MFMA GEMM mainloop ----------------
__device__ __forceinline__ void gemm_mainloop(const u16* __restrict__ A, int lda, int arow0,
                                              const u16* __restrict__ B, int ldb, int brow0, int brmax,
                                              int K, f32x4 (&acc)[4][4], u16* As, u16* Bs) {
    int tid = threadIdx.x;
    int lane = tid & 63;
    int wm = ((tid >> 6) >> 1) * 64, wn = ((tid >> 6) & 1) * 64;
    int srow = tid >> 3;
    int sw = (tid & 7) ^ (srow & 7);
    int ldsoff = tid * 8;
    for (int kt = 0; kt < K; kt += 64) {
        __syncthreads();
#pragma unroll
        for (int i = 0; i < 4; i++) {
            int ar = arow0 + i * 32 + srow;
            const u16* ga = A + (size_t)ar * lda + kt + sw * 8;
            __builtin_amdgcn_global_load_lds((AS1 void*)ga, (AS3 void*)(As + i * 2048 + ldsoff), 16, 0, 0);
            int br = brow0 + i * 32 + srow; if (br > brmax) br = brmax;
            const u16* gb = B + (size_t)br * ldb + kt + sw * 8;
            __builtin_amdgcn_global_load_lds((AS1 void*)gb, (AS3 void*)(Bs + i * 2048 + ldsoff), 16, 0, 0);
        }
        __syncthreads();
#pragma unroll
        for (int kk = 0; kk < 2; kk++) {
            bf16x8 af[4], bfv[4];
            int ks = kk * 4 + (lane >> 4);
#pragma unroll
            for (int mi = 0; mi < 4; mi++) {
                int r = wm + mi * 16 + (lane & 15);
                af[mi] = *(const bf16x8*)(As + r * 64 + (ks ^ (r & 7)) * 8);
            }
#pragma unroll
            for (int ni = 0; ni < 4; ni++) {
                int r = wn + ni * 16 + (lane & 15);
                bfv[ni] = *(const bf16x8*)(Bs + r * 64 + (ks ^ (r & 7)) * 8);
            }
#pragma unroll
            for (int mi = 0; mi < 4; mi++)
#pragma unroll
                for (int ni = 0; ni < 4; ni++)
                    acc[mi][ni] = __builtin_amdgcn_mfma_f32_16x16x32_bf16(af[mi], bfv[ni], acc[mi][ni], 0, 0, 0);
        }
    }
}

// ================= MEGA 3: Q GEMM (512 blocks) | KV GEMM (80 blocks) =================
__global__ __launch_bounds__(256) void mega3_kernel(const u16* __restrict__ qwb,
                                                    const u16* __restrict__ xT,
                                                    const float* __restrict__ qbias,
                                                    u16* __restrict__ qt,
                                                    const u16* __restrict__ kvwb,
                                                    const u16* __restrict__ eb,
                                                    const float* __restrict__ kvbias,
                                                    u16* __restrict__ kvo) {
    __shared__ __align__(16) u16 As[128 * 64];
    __shared__ __align__(16) u16 Bs[128 * 64];
    int bid = blockIdx.x;
    int lane = threadIdx.x & 63, wid = threadIdx.x >> 6;
    int wm = (wid >> 1) * 64, wn = (wid & 1) * 64;
    f32x4 acc[4][4];
#pragma unroll
    for (int mi = 0; mi < 4; mi++)
#pragma unroll
        for (int ni = 0; ni < 4; ni++) acc[mi][ni] = 0.f;

    if (bid < 512) {
        int n = bid >> 5, r = bid & 31;
        int brow0 = (r & 7) * 128, arow0 = (r >> 3) * 128;
        gemm_mainloop(qwb, C_, arow0, xT + (size_t)n * HW_ * C_, C_, brow0, HW_ - 1, C_, acc, As, Bs);
        u16* CT = qt + (size_t)n * HW_ * C_;
        const float* qbn = qbias + n * C_;
#pragma unroll
        for (int mi = 0; mi < 4; mi++) {
            int row = arow0 + wm + mi * 16 + ((lane >> 4) << 2);
            float4 b4 = *(const float4*)(qbn + row);
#pragma unroll
            for (int ni = 0; ni < 4; ni++) {
                int col = brow0 + wn + ni * 16 + (lane & 15);
                f32x4 v = acc[mi][ni];
                ushort4 w;
                w.x = f2bf(v.x + b4.x); w.y = f2bf(v.y + b4.y);
                w.z = f2bf(v.z + b4.z); w.w = f2bf(v.w + b4.w);
                *(ushort4*)(CT + (size_t)col * C_ + row) = w;
            }
        }
    } else {
        int t = bid - 512;
        int brow0 = (t % 10) * 128, arow0 = (t / 10) * 128;
        gemm_mainloop(kvwb, CE_, arow0, eb, CE_, brow0, TOK_ - 1, CE_, acc, As, Bs);
#pragma unroll
        for (int mi = 0; mi < 4; mi++) {
            int row = arow0 + wm + mi * 16 + ((lane >> 4) << 2);
            float4 b4 = *(const float4*)(kvbias + row);
#pragma unroll
            for (int ni = 0; ni < 4; ni++) {
                int col = brow0 + wn + ni * 16 + (lane & 15);
                if (col < TOK_) {
                    f32x4 v = acc[mi][ni];
                    ushort4 w;
                    w.x = f2bf(v.x + b4.x); w.y = f2bf(v.y + b4.y);
                    w.z = f2bf(v.z + b4.z); w.w = f2bf(v.w + b4.w);
                    *(ushort4*)(kvo + (size_t)col * 1024 + row) = w;
                }
            }
        }
    }
}

// ---------------- OUT GEMM ----------------
__global__ __launch_bounds__(256) void gemm_out_mfma(const u16* __restrict__ owb,
                                                     const u16* __restrict__ yT,
                                                     const float* __restrict__ ob,
                                                     const float* __restrict__ inp,
                                                     float* __restrict__ outp) {
    __shared__ __align__(16) u16 As[128 * 64];
    __shared__ __align__(16) u16 Bs[128 * 64];
    int n = blockIdx.z;
    int arow0 = blockIdx.y * 128, brow0 = blockIdx.x * 128;
    f32x4 acc[4][4];
#pragma unroll
    for (int mi = 0; mi < 4; mi++)
#pragma unroll
        for (int ni = 0; ni < 4; ni++) acc[mi][ni] = 0.f;
    gemm_mainloop(owb, C_, arow0, yT + (size_t)n * HW_ * C_, C_, brow0, HW_ - 1, C_, acc, As, Bs);
    int lane = threadIdx.x & 63, wid = threadIdx.x >> 6;
    int wm = (wid >> 1) * 64, wn = (wid & 1) * 64;
    float* Co = outp + (size_t)n * C_ * HW_;
    const float* In = inp + (size_t)n * C_ * HW_;
#pragma unroll
    for (int mi = 0; mi < 4; mi++) {
        int row = arow0 + wm + mi * 16 + ((lane >> 4) << 2);
        float4 b4 = *(const float4*)(ob + row);
#pragma unroll
        for (int ni = 0; ni < 4; ni++) {
            int col = brow0 + wn + ni * 16 + (lane & 15);
            f32x4 v = acc[mi][ni];
            size_t i0 = (size_t)row * HW_ + col;
            Co[i0]            = v.x + b4.x + In[i0];
            Co[i0 + HW_]      = v.y + b4.y + In[i0 + HW_];
            Co[i0 + 2 * HW_]  = v.z + b4.z + In[i0 + 2 * HW_];
            Co[i0 + 3 * HW_]  = v.w + b4.w + In[i0 + 3 * HW_];
        }
    }
}

// ---------------- MFMA attention: 4 q-blocks (256 q-rows) per block, K/V staged once ----------------
__global__ __launch_bounds__(256) void attn_mfma(const u16* __restrict__ kvb,
                                                 const float* __restrict__ mask,
                                                 const u16* __restrict__ qt,
                                                 u16* __restrict__ yt) {
    int nh = blockIdx.x;
    int n = nh >> 3, h = nh & 7;
    __shared__ __align__(16) u16 Qs[64 * 64];
    __shared__ __align__(16) u16 Ks[80 * 64];
    __shared__ __align__(16) u16 VT[64 * 104];
    __shared__ __align__(16) u16 Ps[64 * 104];
    __shared__ float msk[80];
    int tid = threadIdx.x;
    int lane = tid & 63, w = tid >> 6;
    int g = lane >> 4, l15 = lane & 15;

    // ---- stage K / VT / P-pad / mask ONCE ----
    const u16* kbase = kvb + (size_t)(n * S_) * 1024 + h * 64;
#pragma unroll
    for (int pass = 0; pass < 3; pass++) {
        int idx = pass * 256 + tid;
        if (idx < 640) {
            int row = idx >> 3, slot = idx & 7;
            int srow = row < S_ ? row : S_ - 1;
            int sw = slot ^ (row & 7);
            __builtin_amdgcn_global_load_lds((AS1 void*)(kbase + (size_t)srow * 1024 + sw * 8),
                                             (AS3 void*)(Ks + idx * 8), 16, 0, 0);
        }
    }
    {
        int d = tid & 63, sg = tid >> 6;
        const u16* vbase = kvb + (size_t)(n * S_) * 1024 + 512 + h * 64 + d;
        for (int s = sg; s < 104; s += 4) {
            u16 v = (s < S_) ? vbase[(size_t)s * 1024] : (u16)0;
            VT[d * 104 + s] = v;
        }
    }
    for (int i = tid; i < 512; i += 256) {
        int r = i >> 3, cp = i & 7;
        *(unsigned*)&Ps[r * 104 + 80 + cp * 2] = 0u;
    }
    if (tid < 80) msk[tid] = (tid < S_) ? mask[n * S_ + tid] * 10000.f : 0.f;

    int qrow = w * 16 + l15;

    for (int qi = 0; qi < 4; qi++) {
        int qb = blockIdx.y * 4 + qi;
        __syncthreads();   // prior-iter Qs reads done (iter 0: aligns everyone)
        const u16* qbase = qt + ((size_t)(n * HW_ + qb * 64)) * C_ + h * 64;
#pragma unroll
        for (int pass = 0; pass < 2; pass++) {
            int idx = pass * 256 + tid;
            int row = idx >> 3, slot = idx & 7;
            int sw = slot ^ (row & 7);
            __builtin_amdgcn_global_load_lds((AS1 void*)(qbase + (size_t)row * C_ + sw * 8),
                                             (AS3 void*)(Qs + idx * 8), 16, 0, 0);
        }
        __syncthreads();   // Qs ready; iter 0: K/VT/pad/msk ready too

        bf16x8 qf[2];
#pragma unroll
        for (int kk = 0; kk < 2; kk++) {
            int s8 = kk * 4 + g;
            qf[kk] = *(const bf16x8*)(Qs + qrow * 64 + (s8 ^ (qrow & 7)) * 8);
        }
        f32x4 sc[5];
#pragma unroll
        for (int kb = 0; kb < 5; kb++) {
            sc[kb] = 0.f;
#pragma unroll
            for (int kk = 0; kk < 2; kk++) {
                int r = kb * 16 + l15;
                int s8 = kk * 4 + g;
                bf16x8 kf = *(const bf16x8*)(Ks + r * 64 + (s8 ^ (r & 7)) * 8);
                sc[kb] = __builtin_amdgcn_mfma_f32_16x16x32_bf16(kf, qf[kk], sc[kb], 0, 0, 0);
            }
        }
        float sv[5][4];
        float mx = -3e38f;
#pragma unroll
        for (int kb = 0; kb < 5; kb++)
#pragma unroll
            for (int j = 0; j < 4; j++) {
                int key = kb * 16 + g * 4 + j;
                float s = sc[kb][j] * 0.125f - msk[key];
                sv[kb][j] = s;
                if (key < S_) mx = fmaxf(mx, s);
            }
        mx = fmaxf(mx, __shfl_xor(mx, 16));
        mx = fmaxf(mx, __shfl_xor(mx, 32));
        float sum = 0.f;
        float p[5][4];
#pragma unroll
        for (int kb = 0; kb < 5; kb++)
#pragma unroll
            for (int j = 0; j < 4; j++) {
                int key = kb * 16 + g * 4 + j;
                float pv = (key < S_) ? __expf(sv[kb][j] - mx) : 0.f;
                p[kb][j] = pv;
                sum += pv;
            }
        sum += __shfl_xor(sum, 16);
        sum += __shfl_xor(sum, 32);
        float inv = 1.f / sum;
#pragma unroll
        for (int kb = 0; kb < 5; kb++) {
            unsigned lo = (unsigned)f2bf(p[kb][0] * inv) | ((unsigned)f2bf(p[kb][1] * inv) << 16);
            unsigned hi = (unsigned)f2bf(p[kb][2] * inv) | ((unsigned)f2bf(p[kb][3] * inv) << 16);
            int col = kb * 16 + g * 4;
            *(uint2*)&Ps[qrow * 104 + col] = make_uint2(lo, hi);
        }
        f32x4 ya[4];
#pragma unroll
        for (int mf = 0; mf < 4; mf++) ya[mf] = 0.f;
#pragma unroll
        for (int kk = 0; kk < 3; kk++) {
            int s8 = kk * 4 + g;
            bf16x8 pf = *(const bf16x8*)(Ps + qrow * 104 + s8 * 8);
#pragma unroll
            for (int mf = 0; mf < 4; mf++) {
                bf16x8 vf = *(const bf16x8*)(VT + (mf * 16 + l15) * 104 + s8 * 8);
                ya[mf] = __builtin_amdgcn_mfma_f32_16x16x32_bf16(vf, pf, ya[mf], 0, 0, 0);
            }
        }
        u16* yrow = yt + ((size_t)(n * HW_ + qb * 64 + qrow)) * C_ + h * 64;
#pragma unroll
        for (int mf = 0; mf < 4; mf++) {
            int d0 = mf * 16 + g * 4;
            ushort4 o;
            o.x = f2bf(ya[mf][0]); o.y = f2bf(ya[mf][1]);
            o.z = f2bf(ya[mf][2]); o.w = f2bf(ya[mf][3]);
            *(ushort4*)(yrow + d0) = o;
        }
    }
}

extern "C" void kernel_launch(void* const* d_in, const int* in_sizes, int n_in,
                              void* d_out, int out_size, void* d_ws, size_t ws_size,
                              hipStream_t stream) {
    const float* inp  = (const float*)d_in[0];
    const float* cond = (const float*)d_in[1];
    const float* enc  = (const float*)d_in[2];
    const float* mask = (const float*)d_in[3];
    const float* agw  = (const float*)d_in[4];
    const float* agb  = (const float*)d_in[5];
    const float* lnw  = (const float*)d_in[6];
    const float* lnb  = (const float*)d_in[7];
    const float* qw   = (const float*)d_in[8];
    const float* qb   = (const float*)d_in[9];
    const float* kvw  = (const float*)d_in[10];
    const float* kvb  = (const float*)d_in[11];
    const float* ow   = (const float*)d_in[12];
    const float* ob   = (const float*)d_in[13];
    float* ws  = (float*)d_ws;
    float* out = (float*)d_out;
    u16* wsu = (u16*)((char*)d_ws + WSU_BYTE);
    float* ssf = (float*)(wsu + U_QT);     // 16x1024 fp32, consumed before mega3 writes qt

    // mega1: stats(256) | cvt3(1280) | ln(1232) | gemv_ss(64) = 2832 blocks
    mega1_kernel<<<dim3(2832), 256, 0, stream>>>(inp, ws + WS_PSTAT,
                                                 qw, ow, kvw, wsu + U_QW, wsu + U_OW, wsu + U_KVW,
                                                 enc, lnw, lnb, wsu + U_EB,
                                                 cond, agw, agb, ssf);
    // mega2: xT(2048) | qbias(32) = 2080 blocks
    mega2_kernel<<<dim3(2080), 256, 0, stream>>>(inp, ssf, ws + WS_PSTAT,
                                                 wsu + U_XT, qw, qb, ws + WS_QBIAS);
    // mega3: gemm_q(512) | gemm_kv(80) = 592 blocks
    mega3_kernel<<<dim3(592), 256, 0, stream>>>(wsu + U_QW, wsu + U_XT, ws + WS_QBIAS, wsu + U_QT,
                                                wsu + U_KVW, wsu + U_EB, kvb, wsu + U_KVB);

    // attn: 128 x 4 blocks, 4 q-blocks per block
    attn_mfma<<<dim3(N_ * NH_, 4), 256, 0, stream>>>(
        wsu + U_KVB, mask, wsu + U_QT, wsu + U_XT);   // yT aliases xT (consumed)

    gemm_out_mfma<<<dim3(HW_ / 128, C_ / 128, N_), 256, 0, stream>>>(
        wsu + U_OW, wsu + U_XT, ob, inp, out);
}

// Round 10
// 100.587 us; speedup vs baseline: 1.1294x; 1.0145x over previous
//
#include <hip/hip_runtime.h>
#include <math.h>

typedef unsigned short u16;
typedef __bf16 bf16x8 __attribute__((ext_vector_type(8)));
typedef float f32x4 __attribute__((ext_vector_type(4)));

#define AS1 __attribute__((address_space(1)))
#define AS3 __attribute__((address_space(3)))

#define N_    16
#define C_    512
#define HW_   1024
#define CE_   768
#define S_    77
#define NH_   8
#define D_    64
#define FEATS_ 512
#define EPS_  1e-5f
#define TOK_  (N_ * S_)   // 1232

// fp32 workspace (float offsets)
#define WS_PSTAT 0                  // 256 blocks x 2 partials
#define WS_QBIAS 1024               // 16*512
// u16 (bf16) workspace, base at byte 131072
#define WSU_BYTE 131072
#define U_QW  0
#define U_OW  262144
#define U_KVW 524288
#define U_EB  1310720              // 1232*768
#define U_KVB 2256896              // 1232*1024
#define U_YT  3518464              // yT 16*1024*512 (ssf borrows first 64KB until mega3)
#define U_XT  11907072             // xT (alpha folded)

__device__ __forceinline__ u16 f2bf(float f) {
    unsigned u = __float_as_uint(f);
    return (u16)((u + 0x7FFFu + ((u >> 16) & 1u)) >> 16);
}

// ---------------- MFMA GEMM mainloop ----------------
__device__ __forceinline__ void gemm_mainloop(const u16* __restrict__ A, int lda, int arow0,
                                              const u16* __restrict__ B, int ldb, int brow0, int brmax,
                                              int K, f32x4 (&acc)[4][4], u16* As, u16* Bs) {
    int tid = threadIdx.x;
    int lane = tid & 63;
    int wm = ((tid >> 6) >> 1) * 64, wn = ((tid >> 6) & 1) * 64;
    int srow = tid >> 3;
    int sw = (tid & 7) ^ (srow & 7);
    int ldsoff = tid * 8;
    for (int kt = 0; kt < K; kt += 64) {
        __syncthreads();
#pragma unroll
        for (int i = 0; i < 4; i++) {
            int ar = arow0 + i * 32 + srow;
            const u16* ga = A + (size_t)ar * lda + kt + sw * 8;
            __builtin_amdgcn_global_load_lds((AS1 void*)ga, (AS3 void*)(As + i * 2048 + ldsoff), 16, 0, 0);
            int br = brow0 + i * 32 + srow; if (br > brmax) br = brmax;
            const u16* gb = B + (size_t)br * ldb + kt + sw * 8;
            __builtin_amdgcn_global_load_lds((AS1 void*)gb, (AS3 void*)(Bs + i * 2048 + ldsoff), 16, 0, 0);
        }
        __syncthreads();
#pragma unroll
        for (int kk = 0; kk < 2; kk++) {
            bf16x8 af[4], bfv[4];
            int ks = kk * 4 + (lane >> 4);
#pragma unroll
            for (int mi = 0; mi < 4; mi++) {
                int r = wm + mi * 16 + (lane & 15);
                af[mi] = *(const bf16x8*)(As + r * 64 + (ks ^ (r & 7)) * 8);
            }
#pragma unroll
            for (int ni = 0; ni < 4; ni++) {
                int r = wn + ni * 16 + (lane & 15);
                bfv[ni] = *(const bf16x8*)(Bs + r * 64 + (ks ^ (r & 7)) * 8);
            }
#pragma unroll
            for (int mi = 0; mi < 4; mi++)
#pragma unroll
                for (int ni = 0; ni < 4; ni++)
                    acc[mi][ni] = __builtin_amdgcn_mfma_f32_16x16x32_bf16(af[mi], bfv[ni], acc[mi][ni], 0, 0, 0);
        }
    }
}

// ================= MEGA 1: stats partials | weight cvt | LN(enc) | gemv ss =================
__global__ __launch_bounds__(256) void mega1_kernel(const float* __restrict__ inp,
                                                    float* __restrict__ pstats,
                                                    const float* __restrict__ qw,
                                                    const float* __restrict__ ow,
                                                    const float* __restrict__ kvw,
                                                    u16* __restrict__ uq,
                                                    u16* __restrict__ uo,
                                                    u16* __restrict__ ukv,
                                                    const float* __restrict__ enc,
                                                    const float* __restrict__ lnw,
                                                    const float* __restrict__ lnb,
                                                    u16* __restrict__ eb,
                                                    const float* __restrict__ cond,
                                                    const float* __restrict__ agw,
                                                    const float* __restrict__ agb,
                                                    float* __restrict__ ssf) {
    __shared__ __align__(16) float smem[16384];   // 64KB union
    int bid = blockIdx.x;
    int tid = threadIdx.x;
    if (bid < 256) {
        int n = bid >> 4, slice = bid & 15;
        const float* base = inp + (size_t)n * C_ * HW_ + slice * (C_ * HW_ / 16);
        float s = 0.f, s2 = 0.f;
        const float4* b4 = (const float4*)base;
        for (int i = tid; i < (C_ * HW_ / 16) / 4; i += 256) {
            float4 v = b4[i];
            s  += v.x + v.y + v.z + v.w;
            s2 += v.x * v.x + v.y * v.y + v.z * v.z + v.w * v.w;
        }
        for (int off = 32; off; off >>= 1) {
            s  += __shfl_down(s, off);
            s2 += __shfl_down(s2, off);
        }
        int wid = tid >> 6, lane = tid & 63;
        if (lane == 0) { smem[wid] = s; smem[4 + wid] = s2; }
        __syncthreads();
        if (tid == 0) {
            pstats[bid * 2]     = smem[0] + smem[1] + smem[2] + smem[3];
            pstats[bid * 2 + 1] = smem[4] + smem[5] + smem[6] + smem[7];
        }
    } else if (bid < 1536) {
        int i = (bid - 256) * 256 + tid;
        const float* s; u16* d; int j;
        if (i < 65536)       { s = qw;  d = uq;  j = i; }
        else if (i < 131072) { s = ow;  d = uo;  j = i - 65536; }
        else                 { s = kvw; d = ukv; j = i - 131072; }
        float4 v = ((const float4*)s)[j];
        ushort4 w;
        w.x = f2bf(v.x); w.y = f2bf(v.y); w.z = f2bf(v.z); w.w = f2bf(v.w);
        ((ushort4*)(d))[j] = w;
    } else if (bid < 2768) {
        int tok = bid - 1536;
        const float* row = enc + (size_t)tok * CE_;
        int t = tid;
        float v0 = row[t], v1 = row[t + 256], v2 = row[t + 512];
        float sum = v0 + v1 + v2;
        float sq  = v0 * v0 + v1 * v1 + v2 * v2;
        for (int off = 32; off; off >>= 1) {
            sum += __shfl_down(sum, off);
            sq  += __shfl_down(sq, off);
        }
        int wid = t >> 6, lane = t & 63;
        if (lane == 0) { smem[wid] = sum; smem[4 + wid] = sq; }
        __syncthreads();
        float tot = smem[0] + smem[1] + smem[2] + smem[3];
        float tsq = smem[4] + smem[5] + smem[6] + smem[7];
        float mu  = tot / CE_;
        float var = tsq / CE_ - mu * mu;
        float rstd = rsqrtf(var + EPS_);
        u16* o = eb + (size_t)tok * CE_;
        o[t]       = f2bf((v0 - mu) * rstd * lnw[t] + lnb[t]);
        o[t + 256] = f2bf((v1 - mu) * rstd * lnw[t + 256] + lnb[t + 256]);
        o[t + 512] = f2bf((v2 - mu) * rstd * lnw[t + 512] + lnb[t + 512]);
    } else {
        float (*wz)[512] = (float(*)[512])smem;
        float (*cz)[512] = (float(*)[512])(smem + 8192);
        int r0 = (bid - 2768) * 16;
        for (int i = tid; i < 2048; i += 256) {
            int row = i >> 7, f4 = i & 127;
            *(float4*)&cz[row][f4 * 4] = ((const float4*)(cond + (size_t)row * 512))[f4];
            *(float4*)&wz[row][f4 * 4] = ((const float4*)(agw + (size_t)(r0 + row) * 512))[f4];
        }
        __syncthreads();
        int n = tid >> 4, r = tid & 15;
        float acc = agb[r0 + r];
        for (int i = 0; i < 128; i++) {
            int j = (r + i) & 127;
            float4 c4 = *(const float4*)&cz[n][j * 4];
            float4 w4 = *(const float4*)&wz[r][j * 4];
            acc += c4.x * w4.x + c4.y * w4.y + c4.z * w4.z + c4.w * w4.w;
        }
        ssf[(size_t)n * 1024 + r0 + r] = acc;
    }
}

// ===== MEGA 2: xT (alpha inline, 2048) | qbias gemv (32) | KV GEMM (80) =====
__global__ __launch_bounds__(256) void mega2_kernel(const float* __restrict__ inp,
                                                    const float* __restrict__ ssf,
                                                    const float* __restrict__ pstats,
                                                    u16* __restrict__ xT,
                                                    const float* __restrict__ qw,
                                                    const float* __restrict__ qb,
                                                    float* __restrict__ qbias,
                                                    const u16* __restrict__ kvwb,
                                                    const u16* __restrict__ eb,
                                                    const float* __restrict__ kvbias,
                                                    u16* __restrict__ kvo) {
    __shared__ __align__(16) float smem[16384];
    __shared__ float muS[16], rsS[16];
    int bid = blockIdx.x;
    int tid = threadIdx.x;
    float cnt = (float)(C_ * HW_);
    if (bid < 2048) {
        int n = bid >> 7, rem = bid & 127;
        int c0 = (rem >> 4) * 64, h0 = (rem & 15) * 64;
        float s = 0.f, s2 = 0.f;
        for (int k = 0; k < 16; k++) {
            s  += pstats[(n * 16 + k) * 2];
            s2 += pstats[(n * 16 + k) * 2 + 1];
        }
        float mu = s / cnt;
        float rstd = rsqrtf(s2 / cnt - mu * mu + EPS_);
        float (*t)[65] = (float(*)[65])smem;
        int rr = tid >> 4, cc = (tid & 15) * 4;
#pragma unroll
        for (int i = 0; i < 4; i++) {
            int cl = rr + i * 16;
            int c = c0 + cl;
            float a = rstd * (ssf[(size_t)n * 1024 + c] + 1.f);
            float4 v = *(const float4*)(inp + ((size_t)n * C_ + c) * HW_ + h0 + cc);
            t[cl][cc + 0] = v.x * a; t[cl][cc + 1] = v.y * a;
            t[cl][cc + 2] = v.z * a; t[cl][cc + 3] = v.w * a;
        }
        __syncthreads();
#pragma unroll
        for (int i = 0; i < 4; i++) {
            int hl = rr + i * 16;
            ushort4 w;
            w.x = f2bf(t[cc + 0][hl]); w.y = f2bf(t[cc + 1][hl]);
            w.z = f2bf(t[cc + 2][hl]); w.w = f2bf(t[cc + 3][hl]);
            *(ushort4*)(xT + ((size_t)n * HW_ + h0 + hl) * C_ + c0 + cc) = w;
        }
    } else if (bid < 2080) {
        float (*wz)[512] = (float(*)[512])smem;
        float (*cz)[512] = (float(*)[512])(smem + 8192);
        int r0 = (bid - 2048) * 16;
        if (tid < 16) {
            float s = 0.f, s2 = 0.f;
            for (int k = 0; k < 16; k++) {
                s  += pstats[(tid * 16 + k) * 2];
                s2 += pstats[(tid * 16 + k) * 2 + 1];
            }
            float mu = s / cnt;
            muS[tid] = mu;
            rsS[tid] = rsqrtf(s2 / cnt - mu * mu + EPS_);
        }
        __syncthreads();
        for (int i = tid; i < 2048; i += 256) {
            int row = i >> 7, f4 = i & 127;
            float4 sc4 = ((const float4*)(ssf + (size_t)row * 1024))[f4];
            float4 sh4 = ((const float4*)(ssf + (size_t)row * 1024 + 512))[f4];
            float mu = muS[row], rs = rsS[row];
            float4 b;
            b.x = sh4.x - mu * (rs * (sc4.x + 1.f));
            b.y = sh4.y - mu * (rs * (sc4.y + 1.f));
            b.z = sh4.z - mu * (rs * (sc4.z + 1.f));
            b.w = sh4.w - mu * (rs * (sc4.w + 1.f));
            *(float4*)&cz[row][f4 * 4] = b;
            *(float4*)&wz[row][f4 * 4] = ((const float4*)(qw + (size_t)(r0 + row) * 512))[f4];
        }
        __syncthreads();
        int n = tid >> 4, r = tid & 15;
        float acc = qb[r0 + r];
        for (int i = 0; i < 128; i++) {
            int j = (r + i) & 127;
            float4 c4 = *(const float4*)&cz[n][j * 4];
            float4 w4 = *(const float4*)&wz[r][j * 4];
            acc += c4.x * w4.x + c4.y * w4.y + c4.z * w4.z + c4.w * w4.w;
        }
        qbias[(size_t)n * 512 + r0 + r] = acc;
    } else {
        // ---- KV GEMM: kvo[token][j] = kvb[j] + eb[token] . kvw[j] ----
        u16* As = (u16*)smem;
        u16* Bs = (u16*)smem + 8192;
        int t = bid - 2080;
        int brow0 = (t % 10) * 128, arow0 = (t / 10) * 128;
        f32x4 acc[4][4];
#pragma unroll
        for (int mi = 0; mi < 4; mi++)
#pragma unroll
            for (int ni = 0; ni < 4; ni++) acc[mi][ni] = 0.f;
        gemm_mainloop(kvwb, CE_, arow0, eb, CE_, brow0, TOK_ - 1, CE_, acc, As, Bs);
        int lane = tid & 63, wid = tid >> 6;
        int wm = (wid >> 1) * 64, wn = (wid & 1) * 64;
        int g = lane >> 4, l15 = lane & 15;
#pragma unroll
        for (int mi = 0; mi < 4; mi++) {
            int row = arow0 + wm + mi * 16 + (g << 2);
            float4 b4 = *(const float4*)(kvbias + row);
#pragma unroll
            for (int ni = 0; ni < 4; ni++) {
                int col = brow0 + wn + ni * 16 + l15;
                if (col < TOK_) {
                    f32x4 v = acc[mi][ni];
                    ushort4 wv;
                    wv.x = f2bf(v[0] + b4.x); wv.y = f2bf(v[1] + b4.y);
                    wv.z = f2bf(v[2] + b4.z); wv.w = f2bf(v[3] + b4.w);
                    *(ushort4*)(kvo + (size_t)col * 1024 + row) = wv;
                }
            }
        }
    }
}

// ===== MEGA 3: fused Q GEMM + attention (512 blocks) =====
// Block (n, arow0, brow0): GEMM 128(o) x 128(hw) = 2 complete heads of Q.
// acc(+qbias) -> Qs2 in LDS (aliases As/Bs), per head: stage K/VT, softmax+PV,
// write yT directly. qt never touches HBM. kvo is complete (produced by mega2).
__global__ __launch_bounds__(256) void mega3_kernel(const u16* __restrict__ qwb,
                                                    const u16* __restrict__ xT,
                                                    const float* __restrict__ qbias,
                                                    const u16* __restrict__ kvo,
                                                    const float* __restrict__ mask,
                                                    u16* __restrict__ yt) {
    __shared__ __align__(16) u16 pool[16384];     // As+Bs during GEMM; Qs2 (128x128) after
    __shared__ __align__(16) u16 Ks[80 * 64];
    __shared__ __align__(16) u16 VT[64 * 104];
    __shared__ __align__(16) u16 Ps[64 * 104];
    __shared__ float msk[80];
    u16* As = pool;
    u16* Bs = pool + 8192;
    int bid = blockIdx.x;
    int tid = threadIdx.x;
    int lane = tid & 63, w = tid >> 6;
    int g = lane >> 4, l15 = lane & 15;
    int wm = (w >> 1) * 64, wn = (w & 1) * 64;
    f32x4 acc[4][4];
#pragma unroll
    for (int mi = 0; mi < 4; mi++)
#pragma unroll
        for (int ni = 0; ni < 4; ni++) acc[mi][ni] = 0.f;

    int n = bid >> 5, r = bid & 31;
    int brow0 = (r & 7) * 128, arow0 = (r >> 3) * 128;
    gemm_mainloop(qwb, C_, arow0, xT + (size_t)n * HW_ * C_, C_, brow0, HW_ - 1, C_, acc, As, Bs);
    __syncthreads();   // all waves done reading As/Bs before Qs2 overwrite

    // acc + qbias -> Qs2[hw_loc][o_loc] bf16, swizzled per 64-wide head segment
    const float* qbn = qbias + n * C_;
#pragma unroll
    for (int mi = 0; mi < 4; mi++) {
        int o_loc = wm + mi * 16 + g * 4;
        float4 b4 = *(const float4*)(qbn + arow0 + o_loc);
#pragma unroll
        for (int ni = 0; ni < 4; ni++) {
            int hw_loc = wn + ni * 16 + l15;
            f32x4 v = acc[mi][ni];
            ushort4 wv;
            wv.x = f2bf(v[0] + b4.x); wv.y = f2bf(v[1] + b4.y);
            wv.z = f2bf(v[2] + b4.z); wv.w = f2bf(v[3] + b4.w);
            int dd = o_loc & 63, hsel = o_loc >> 6;
            int col = hsel * 64 + (((dd >> 3) ^ (hw_loc & 7)) << 3) + (dd & 7);
            *(ushort4*)&pool[hw_loc * 128 + col] = wv;
        }
    }
    for (int i = tid; i < 512; i += 256) {
        int rr = i >> 3, cp = i & 7;
        *(unsigned*)&Ps[rr * 104 + 80 + cp * 2] = 0u;
    }
    if (tid < 80) msk[tid] = (tid < S_) ? mask[n * S_ + tid] * 10000.f : 0.f;
    __syncthreads();   // Qs2 + pad + msk visible

    int h_base = arow0 >> 6;
    for (int hl = 0; hl < 2; hl++) {
        int h = h_base + hl;
        if (hl) __syncthreads();   // prior head's Ks/VT reads done
        const u16* kbase = kvo + (size_t)(n * S_) * 1024 + h * 64;
#pragma unroll
        for (int pass = 0; pass < 3; pass++) {
            int idx = pass * 256 + tid;
            if (idx < 640) {
                int row = idx >> 3, slot = idx & 7;
                int srow = row < S_ ? row : S_ - 1;
                int sw = slot ^ (row & 7);
                __builtin_amdgcn_global_load_lds((AS1 void*)(kbase + (size_t)srow * 1024 + sw * 8),
                                                 (AS3 void*)(Ks + idx * 8), 16, 0, 0);
            }
        }
        {
            int d = tid & 63, sg = tid >> 6;
            const u16* vbase = kvo + (size_t)(n * S_) * 1024 + 512 + h * 64 + d;
            for (int s = sg; s < 104; s += 4) {
                u16 v = (s < S_) ? vbase[(size_t)s * 1024] : (u16)0;
                VT[d * 104 + s] = v;
            }
        }
        __syncthreads();   // Ks/VT ready

        for (int qhalf = 0; qhalf < 2; qhalf++) {
            int qrl = qhalf * 64 + w * 16 + l15;   // local hw row 0..127
            bf16x8 qf[2];
#pragma unroll
            for (int kk = 0; kk < 2; kk++) {
                int s8 = kk * 4 + g;
                qf[kk] = *(const bf16x8*)(pool + qrl * 128 + hl * 64 + ((s8 ^ (qrl & 7)) << 3));
            }
            f32x4 sc[5];
#pragma unroll
            for (int kb = 0; kb < 5; kb++) {
                sc[kb] = 0.f;
#pragma unroll
                for (int kk = 0; kk < 2; kk++) {
                    int rr = kb * 16 + l15;
                    int s8 = kk * 4 + g;
                    bf16x8 kf = *(const bf16x8*)(Ks + rr * 64 + ((s8 ^ (rr & 7)) << 3));
                    sc[kb] = __builtin_amdgcn_mfma_f32_16x16x32_bf16(kf, qf[kk], sc[kb], 0, 0, 0);
                }
            }
            float sv[5][4];
            float mx = -3e38f;
#pragma unroll
            for (int kb = 0; kb < 5; kb++)
#pragma unroll
                for (int j = 0; j < 4; j++) {
                    int key = kb * 16 + g * 4 + j;
                    float s = sc[kb][j] * 0.125f - msk[key];
                    sv[kb][j] = s;
                    if (key < S_) mx = fmaxf(mx, s);
                }
            mx = fmaxf(mx, __shfl_xor(mx, 16));
            mx = fmaxf(mx, __shfl_xor(mx, 32));
            float sum = 0.f;
            float p[5][4];
#pragma unroll
            for (int kb = 0; kb < 5; kb++)
#pragma unroll
                for (int j = 0; j < 4; j++) {
                    int key = kb * 16 + g * 4 + j;
                    float pv = (key < S_) ? __expf(sv[kb][j] - mx) : 0.f;
                    p[kb][j] = pv;
                    sum += pv;
                }
            sum += __shfl_xor(sum, 16);
            sum += __shfl_xor(sum, 32);
            float inv = 1.f / sum;
            int prow = w * 16 + l15;   // wave-private Ps row
#pragma unroll
            for (int kb = 0; kb < 5; kb++) {
                unsigned lo = (unsigned)f2bf(p[kb][0] * inv) | ((unsigned)f2bf(p[kb][1] * inv) << 16);
                unsigned hi = (unsigned)f2bf(p[kb][2] * inv) | ((unsigned)f2bf(p[kb][3] * inv) << 16);
                int col = kb * 16 + g * 4;
                *(uint2*)&Ps[prow * 104 + col] = make_uint2(lo, hi);
            }
            f32x4 ya[4];
#pragma unroll
            for (int mf = 0; mf < 4; mf++) ya[mf] = 0.f;
#pragma unroll
            for (int kk = 0; kk < 3; kk++) {
                int s8 = kk * 4 + g;
                bf16x8 pf = *(const bf16x8*)(Ps + prow * 104 + s8 * 8);
#pragma unroll
                for (int mf = 0; mf < 4; mf++) {
                    bf16x8 vf = *(const bf16x8*)(VT + (mf * 16 + l15) * 104 + s8 * 8);
                    ya[mf] = __builtin_amdgcn_mfma_f32_16x16x32_bf16(vf, pf, ya[mf], 0, 0, 0);
                }
            }
            u16* yrow = yt + ((size_t)(n * HW_ + brow0 + qrl)) * C_ + h * 64;
#pragma unroll
            for (int mf = 0; mf < 4; mf++) {
                int d0 = mf * 16 + g * 4;
                ushort4 o;
                o.x = f2bf(ya[mf][0]); o.y = f2bf(ya[mf][1]);
                o.z = f2bf(ya[mf][2]); o.w = f2bf(ya[mf][3]);
                *(ushort4*)(yrow + d0) = o;
            }
        }
    }
}

// ---------------- OUT GEMM ----------------
__global__ __launch_bounds__(256) void gemm_out_mfma(const u16* __restrict__ owb,
                                                     const u16* __restrict__ yT,
                                                     const float* __restrict__ ob,
                                                     const float* __restrict__ inp,
                                                     float* __restrict__ outp) {
    __shared__ __align__(16) u16 As[128 * 64];
    __shared__ __align__(16) u16 Bs[128 * 64];
    int n = blockIdx.z;
    int arow0 = blockIdx.y * 128, brow0 = blockIdx.x * 128;
    f32x4 acc[4][4];
#pragma unroll
    for (int mi = 0; mi < 4; mi++)
#pragma unroll
        for (int ni = 0; ni < 4; ni++) acc[mi][ni] = 0.f;
    gemm_mainloop(owb, C_, arow0, yT + (size_t)n * HW_ * C_, C_, brow0, HW_ - 1, C_, acc, As, Bs);
    int lane = threadIdx.x & 63, wid = threadIdx.x >> 6;
    int wm = (wid >> 1) * 64, wn = (wid & 1) * 64;
    float* Co = outp + (size_t)n * C_ * HW_;
    const float* In = inp + (size_t)n * C_ * HW_;
#pragma unroll
    for (int mi = 0; mi < 4; mi++) {
        int row = arow0 + wm + mi * 16 + ((lane >> 4) << 2);
        float4 b4 = *(const float4*)(ob + row);
#pragma unroll
        for (int ni = 0; ni < 4; ni++) {
            int col = brow0 + wn + ni * 16 + (lane & 15);
            f32x4 v = acc[mi][ni];
            size_t i0 = (size_t)row * HW_ + col;
            Co[i0]            = v[0] + b4.x + In[i0];
            Co[i0 + HW_]      = v[1] + b4.y + In[i0 + HW_];
            Co[i0 + 2 * HW_]  = v[2] + b4.z + In[i0 + 2 * HW_];
            Co[i0 + 3 * HW_]  = v[3] + b4.w + In[i0 + 3 * HW_];
        }
    }
}

extern "C" void kernel_launch(void* const* d_in, const int* in_sizes, int n_in,
                              void* d_out, int out_size, void* d_ws, size_t ws_size,
                              hipStream_t stream) {
    const float* inp  = (const float*)d_in[0];
    const float* cond = (const float*)d_in[1];
    const float* enc  = (const float*)d_in[2];
    const float* mask = (const float*)d_in[3];
    const float* agw  = (const float*)d_in[4];
    const float* agb  = (const float*)d_in[5];
    const float* lnw  = (const float*)d_in[6];
    const float* lnb  = (const float*)d_in[7];
    const float* qw   = (const float*)d_in[8];
    const float* qb   = (const float*)d_in[9];
    const float* kvw  = (const float*)d_in[10];
    const float* kvb  = (const float*)d_in[11];
    const float* ow   = (const float*)d_in[12];
    const float* ob   = (const float*)d_in[13];
    float* ws  = (float*)d_ws;
    float* out = (float*)d_out;
    u16* wsu = (u16*)((char*)d_ws + WSU_BYTE);
    float* ssf = (float*)(wsu + U_YT);     // 16x1024 fp32, consumed before mega3 writes yT

    // mega1: stats(256) | cvt3(1280) | ln(1232) | gemv_ss(64) = 2832 blocks
    mega1_kernel<<<dim3(2832), 256, 0, stream>>>(inp, ws + WS_PSTAT,
                                                 qw, ow, kvw, wsu + U_QW, wsu + U_OW, wsu + U_KVW,
                                                 enc, lnw, lnb, wsu + U_EB,
                                                 cond, agw, agb, ssf);
    // mega2: xT(2048) | qbias(32) | KV GEMM(80) = 2160 blocks
    mega2_kernel<<<dim3(2160), 256, 0, stream>>>(inp, ssf, ws + WS_PSTAT,
                                                 wsu + U_XT, qw, qb, ws + WS_QBIAS,
                                                 wsu + U_KVW, wsu + U_EB, kvb, wsu + U_KVB);
    // mega3: fused Q-GEMM + attention (512 blocks)
    mega3_kernel<<<dim3(512), 256, 0, stream>>>(wsu + U_QW, wsu + U_XT, ws + WS_QBIAS,
                                                wsu + U_KVB, mask, wsu + U_YT);

    gemm_out_mfma<<<dim3(HW_ / 128, C_ / 128, N_), 256, 0, stream>>>(
        wsu + U_OW, wsu + U_YT, ob, inp, out);
}

// Round 11
// 91.944 us; speedup vs baseline: 1.2355x; 1.0940x over previous
//
#include <hip/hip_runtime.h>
#include <math.h>

typedef unsigned short u16;
typedef __bf16 bf16x8 __attribute__((ext_vector_type(8)));
typedef float f32x4 __attribute__((ext_vector_type(4)));

#define AS1 __attribute__((address_space(1)))
#define AS3 __attribute__((address_space(3)))

#define N_    16
#define C_    512
#define HW_   1024
#define CE_   768
#define S_    77
#define NH_   8
#define D_    64
#define FEATS_ 512
#define EPS_  1e-5f
#define TOK_  (N_ * S_)   // 1232

// fp32 workspace (float offsets)
#define WS_PSTAT 0                  // 256 x 2 partials
#define WS_QBIAS 1024               // 16*512
// u16 (bf16) workspace, base at byte 131072
#define WSU_BYTE 131072
#define U_QW  0
#define U_OW  262144
#define U_KVW 524288
#define U_EB  1310720              // 1232*768
#define U_KVB 2256896              // 1232*1024
#define U_YT  3518464              // yT 16*1024*512 (ssf borrows first 64KB until mega3)
#define U_XT  11907072             // xT (alpha folded)

__device__ __forceinline__ u16 f2bf(float f) {
    unsigned u = __float_as_uint(f);
    return (u16)((u + 0x7FFFu + ((u >> 16) & 1u)) >> 16);
}

// ---------------- MFMA GEMM mainloop ----------------
__device__ __forceinline__ void gemm_mainloop(const u16* __restrict__ A, int lda, int arow0,
                                              const u16* __restrict__ B, int ldb, int brow0, int brmax,
                                              int K, f32x4 (&acc)[4][4], u16* As, u16* Bs) {
    int tid = threadIdx.x;
    int lane = tid & 63;
    int wm = ((tid >> 6) >> 1) * 64, wn = ((tid >> 6) & 1) * 64;
    int srow = tid >> 3;
    int sw = (tid & 7) ^ (srow & 7);
    int ldsoff = tid * 8;
    for (int kt = 0; kt < K; kt += 64) {
        __syncthreads();
#pragma unroll
        for (int i = 0; i < 4; i++) {
            int ar = arow0 + i * 32 + srow;
            const u16* ga = A + (size_t)ar * lda + kt + sw * 8;
            __builtin_amdgcn_global_load_lds((AS1 void*)ga, (AS3 void*)(As + i * 2048 + ldsoff), 16, 0, 0);
            int br = brow0 + i * 32 + srow; if (br > brmax) br = brmax;
            const u16* gb = B + (size_t)br * ldb + kt + sw * 8;
            __builtin_amdgcn_global_load_lds((AS1 void*)gb, (AS3 void*)(Bs + i * 2048 + ldsoff), 16, 0, 0);
        }
        __syncthreads();
#pragma unroll
        for (int kk = 0; kk < 2; kk++) {
            bf16x8 af[4], bfv[4];
            int ks = kk * 4 + (lane >> 4);
#pragma unroll
            for (int mi = 0; mi < 4; mi++) {
                int r = wm + mi * 16 + (lane & 15);
                af[mi] = *(const bf16x8*)(As + r * 64 + (ks ^ (r & 7)) * 8);
            }
#pragma unroll
            for (int ni = 0; ni < 4; ni++) {
                int r = wn + ni * 16 + (lane & 15);
                bfv[ni] = *(const bf16x8*)(Bs + r * 64 + (ks ^ (r & 7)) * 8);
            }
#pragma unroll
            for (int mi = 0; mi < 4; mi++)
#pragma unroll
                for (int ni = 0; ni < 4; ni++)
                    acc[mi][ni] = __builtin_amdgcn_mfma_f32_16x16x32_bf16(af[mi], bfv[ni], acc[mi][ni], 0, 0, 0);
        }
    }
}

// ====== MEGA 1: gemv_ss(64) | stats(256) | weight cvt(1280) | LN(1232) ======
__global__ __launch_bounds__(256) void mega1_kernel(const float* __restrict__ inp,
                                                    float* __restrict__ pstats,
                                                    const float* __restrict__ qw,
                                                    const float* __restrict__ ow,
                                                    const float* __restrict__ kvw,
                                                    u16* __restrict__ uq,
                                                    u16* __restrict__ uo,
                                                    u16* __restrict__ ukv,
                                                    const float* __restrict__ enc,
                                                    const float* __restrict__ lnw,
                                                    const float* __restrict__ lnb,
                                                    u16* __restrict__ eb,
                                                    const float* __restrict__ cond,
                                                    const float* __restrict__ agw,
                                                    const float* __restrict__ agb,
                                                    float* __restrict__ ssf) {
    __shared__ __align__(16) float smem[16384];   // 64KB union
    int bid = blockIdx.x;
    int tid = threadIdx.x;
    if (bid < 64) {
        // ---- gemv_ss (heavy, runs first): ssf[n][r] = agb[r] + dot(cond[n], agw[r]) ----
        float (*wz)[512] = (float(*)[512])smem;
        float (*cz)[512] = (float(*)[512])(smem + 8192);
        int r0 = bid * 16;
        for (int i = tid; i < 2048; i += 256) {
            int row = i >> 7, f4 = i & 127;
            *(float4*)&cz[row][f4 * 4] = ((const float4*)(cond + (size_t)row * 512))[f4];
            *(float4*)&wz[row][f4 * 4] = ((const float4*)(agw + (size_t)(r0 + row) * 512))[f4];
        }
        __syncthreads();
        int n = tid >> 4, r = tid & 15;
        float acc = agb[r0 + r];
        for (int i = 0; i < 128; i++) {
            int j = (r + i) & 127;
            float4 c4 = *(const float4*)&cz[n][j * 4];
            float4 w4 = *(const float4*)&wz[r][j * 4];
            acc += c4.x * w4.x + c4.y * w4.y + c4.z * w4.z + c4.w * w4.w;
        }
        ssf[(size_t)n * 1024 + r0 + r] = acc;
    } else if (bid < 320) {
        // ---- stats: per-block partial sum/sumsq ----
        int b = bid - 64;
        int n = b >> 4, slice = b & 15;
        const float* base = inp + (size_t)n * C_ * HW_ + slice * (C_ * HW_ / 16);
        float s = 0.f, s2 = 0.f;
        const float4* b4 = (const float4*)base;
        for (int i = tid; i < (C_ * HW_ / 16) / 4; i += 256) {
            float4 v = b4[i];
            s  += v.x + v.y + v.z + v.w;
            s2 += v.x * v.x + v.y * v.y + v.z * v.z + v.w * v.w;
        }
        for (int off = 32; off; off >>= 1) {
            s  += __shfl_down(s, off);
            s2 += __shfl_down(s2, off);
        }
        int wid = tid >> 6, lane = tid & 63;
        if (lane == 0) { smem[wid] = s; smem[4 + wid] = s2; }
        __syncthreads();
        if (tid == 0) {
            pstats[b * 2]     = smem[0] + smem[1] + smem[2] + smem[3];
            pstats[b * 2 + 1] = smem[4] + smem[5] + smem[6] + smem[7];
        }
    } else if (bid < 1600) {
        // ---- cvt3: fp32 -> bf16 weights ----
        int i = (bid - 320) * 256 + tid;
        const float* s; u16* d; int j;
        if (i < 65536)       { s = qw;  d = uq;  j = i; }
        else if (i < 131072) { s = ow;  d = uo;  j = i - 65536; }
        else                 { s = kvw; d = ukv; j = i - 131072; }
        float4 v = ((const float4*)s)[j];
        ushort4 w;
        w.x = f2bf(v.x); w.y = f2bf(v.y); w.z = f2bf(v.z); w.w = f2bf(v.w);
        ((ushort4*)(d))[j] = w;
    } else {
        // ---- layernorm(enc) -> eb bf16 ----
        int tok = bid - 1600;
        const float* row = enc + (size_t)tok * CE_;
        int t = tid;
        float v0 = row[t], v1 = row[t + 256], v2 = row[t + 512];
        float sum = v0 + v1 + v2;
        float sq  = v0 * v0 + v1 * v1 + v2 * v2;
        for (int off = 32; off; off >>= 1) {
            sum += __shfl_down(sum, off);
            sq  += __shfl_down(sq, off);
        }
        int wid = t >> 6, lane = t & 63;
        if (lane == 0) { smem[wid] = sum; smem[4 + wid] = sq; }
        __syncthreads();
        float tot = smem[0] + smem[1] + smem[2] + smem[3];
        float tsq = smem[4] + smem[5] + smem[6] + smem[7];
        float mu  = tot / CE_;
        float var = tsq / CE_ - mu * mu;
        float rstd = rsqrtf(var + EPS_);
        u16* o = eb + (size_t)tok * CE_;
        o[t]       = f2bf((v0 - mu) * rstd * lnw[t] + lnb[t]);
        o[t + 256] = f2bf((v1 - mu) * rstd * lnw[t + 256] + lnb[t + 256]);
        o[t + 512] = f2bf((v2 - mu) * rstd * lnw[t + 512] + lnb[t + 512]);
    }
}

// ====== MEGA 2: KV GEMM(80, first) | qbias gemv(32) | xT alpha-transpose(2048) ======
__global__ __launch_bounds__(256) void mega2_kernel(const float* __restrict__ inp,
                                                    const float* __restrict__ ssf,
                                                    const float* __restrict__ pstats,
                                                    u16* __restrict__ xT,
                                                    const float* __restrict__ qw,
                                                    const float* __restrict__ qb,
                                                    float* __restrict__ qbias,
                                                    const u16* __restrict__ kvwb,
                                                    const u16* __restrict__ eb,
                                                    const float* __restrict__ kvbias,
                                                    u16* __restrict__ kvo) {
    __shared__ __align__(16) float smem[16384];
    __shared__ float muS[16], rsS[16];
    int bid = blockIdx.x;
    int tid = threadIdx.x;
    float cnt = (float)(C_ * HW_);
    if (bid < 80) {
        // ---- KV GEMM (longest blocks — dispatched first to overlap xT wave) ----
        u16* As = (u16*)smem;
        u16* Bs = (u16*)smem + 8192;
        int t = bid;
        int brow0 = (t % 10) * 128, arow0 = (t / 10) * 128;
        f32x4 acc[4][4];
#pragma unroll
        for (int mi = 0; mi < 4; mi++)
#pragma unroll
            for (int ni = 0; ni < 4; ni++) acc[mi][ni] = 0.f;
        gemm_mainloop(kvwb, CE_, arow0, eb, CE_, brow0, TOK_ - 1, CE_, acc, As, Bs);
        int lane = tid & 63, wid = tid >> 6;
        int wm = (wid >> 1) * 64, wn = (wid & 1) * 64;
        int g = lane >> 4, l15 = lane & 15;
#pragma unroll
        for (int mi = 0; mi < 4; mi++) {
            int row = arow0 + wm + mi * 16 + (g << 2);
            float4 b4 = *(const float4*)(kvbias + row);
#pragma unroll
            for (int ni = 0; ni < 4; ni++) {
                int col = brow0 + wn + ni * 16 + l15;
                if (col < TOK_) {
                    f32x4 v = acc[mi][ni];
                    ushort4 wv;
                    wv.x = f2bf(v[0] + b4.x); wv.y = f2bf(v[1] + b4.y);
                    wv.z = f2bf(v[2] + b4.z); wv.w = f2bf(v[3] + b4.w);
                    *(ushort4*)(kvo + (size_t)col * 1024 + row) = wv;
                }
            }
        }
    } else if (bid < 112) {
        // ---- qbias[n][r] = qb[r] + dot(beta[n], qw[r]); beta inline ----
        float (*wz)[512] = (float(*)[512])smem;
        float (*cz)[512] = (float(*)[512])(smem + 8192);
        int r0 = (bid - 80) * 16;
        if (tid < 16) {
            float s = 0.f, s2 = 0.f;
            for (int k = 0; k < 16; k++) {
                s  += pstats[(tid * 16 + k) * 2];
                s2 += pstats[(tid * 16 + k) * 2 + 1];
            }
            float mu = s / cnt;
            muS[tid] = mu;
            rsS[tid] = rsqrtf(s2 / cnt - mu * mu + EPS_);
        }
        __syncthreads();
        for (int i = tid; i < 2048; i += 256) {
            int row = i >> 7, f4 = i & 127;
            float4 sc4 = ((const float4*)(ssf + (size_t)row * 1024))[f4];
            float4 sh4 = ((const float4*)(ssf + (size_t)row * 1024 + 512))[f4];
            float mu = muS[row], rs = rsS[row];
            float4 b;
            b.x = sh4.x - mu * (rs * (sc4.x + 1.f));
            b.y = sh4.y - mu * (rs * (sc4.y + 1.f));
            b.z = sh4.z - mu * (rs * (sc4.z + 1.f));
            b.w = sh4.w - mu * (rs * (sc4.w + 1.f));
            *(float4*)&cz[row][f4 * 4] = b;
            *(float4*)&wz[row][f4 * 4] = ((const float4*)(qw + (size_t)(r0 + row) * 512))[f4];
        }
        __syncthreads();
        int n = tid >> 4, r = tid & 15;
        float acc = qb[r0 + r];
        for (int i = 0; i < 128; i++) {
            int j = (r + i) & 127;
            float4 c4 = *(const float4*)&cz[n][j * 4];
            float4 w4 = *(const float4*)&wz[r][j * 4];
            acc += c4.x * w4.x + c4.y * w4.y + c4.z * w4.z + c4.w * w4.w;
        }
        qbias[(size_t)n * 512 + r0 + r] = acc;
    } else {
        // ---- xT[n][hw][c] = input[n][c][hw] * alpha[n][c] ----
        int bid2 = bid - 112;
        int n = bid2 >> 7, rem = bid2 & 127;
        int c0 = (rem >> 4) * 64, h0 = (rem & 15) * 64;
        float s = 0.f, s2 = 0.f;
        for (int k = 0; k < 16; k++) {
            s  += pstats[(n * 16 + k) * 2];
            s2 += pstats[(n * 16 + k) * 2 + 1];
        }
        float mu = s / cnt;
        float rstd = rsqrtf(s2 / cnt - mu * mu + EPS_);
        float (*t)[65] = (float(*)[65])smem;
        int rr = tid >> 4, cc = (tid & 15) * 4;
#pragma unroll
        for (int i = 0; i < 4; i++) {
            int cl = rr + i * 16;
            int c = c0 + cl;
            float a = rstd * (ssf[(size_t)n * 1024 + c] + 1.f);
            float4 v = *(const float4*)(inp + ((size_t)n * C_ + c) * HW_ + h0 + cc);
            t[cl][cc + 0] = v.x * a; t[cl][cc + 1] = v.y * a;
            t[cl][cc + 2] = v.z * a; t[cl][cc + 3] = v.w * a;
        }
        __syncthreads();
#pragma unroll
        for (int i = 0; i < 4; i++) {
            int hl = rr + i * 16;
            ushort4 w;
            w.x = f2bf(t[cc + 0][hl]); w.y = f2bf(t[cc + 1][hl]);
            w.z = f2bf(t[cc + 2][hl]); w.w = f2bf(t[cc + 3][hl]);
            *(ushort4*)(xT + ((size_t)n * HW_ + h0 + hl) * C_ + c0 + cc) = w;
        }
    }
}

// ===== MEGA 3: fused Q GEMM + attention (512 blocks) =====
__global__ __launch_bounds__(256) void mega3_kernel(const u16* __restrict__ qwb,
                                                    const u16* __restrict__ xT,
                                                    const float* __restrict__ qbias,
                                                    const u16* __restrict__ kvo,
                                                    const float* __restrict__ mask,
                                                    u16* __restrict__ yt) {
    __shared__ __align__(16) u16 pool[16384];     // As+Bs during GEMM; Qs2 (128x128) after
    __shared__ __align__(16) u16 Ks[80 * 64];
    __shared__ __align__(16) u16 VT[64 * 104];
    __shared__ __align__(16) u16 Ps[64 * 104];
    __shared__ float msk[80];
    u16* As = pool;
    u16* Bs = pool + 8192;
    int bid = blockIdx.x;
    int tid = threadIdx.x;
    int lane = tid & 63, w = tid >> 6;
    int g = lane >> 4, l15 = lane & 15;
    int wm = (w >> 1) * 64, wn = (w & 1) * 64;
    f32x4 acc[4][4];
#pragma unroll
    for (int mi = 0; mi < 4; mi++)
#pragma unroll
        for (int ni = 0; ni < 4; ni++) acc[mi][ni] = 0.f;

    int n = bid >> 5, r = bid & 31;
    int brow0 = (r & 7) * 128, arow0 = (r >> 3) * 128;
    int h_base = arow0 >> 6;
    gemm_mainloop(qwb, C_, arow0, xT + (size_t)n * HW_ * C_, C_, brow0, HW_ - 1, C_, acc, As, Bs);
    __syncthreads();   // all waves done reading As/Bs before Qs2 overwrite

    // ---- HOISTED head-0 staging: overlaps the Qs2 conversion below ----
    {
        int h = h_base;
        const u16* kbase = kvo + (size_t)(n * S_) * 1024 + h * 64;
#pragma unroll
        for (int pass = 0; pass < 3; pass++) {
            int idx = pass * 256 + tid;
            if (idx < 640) {
                int row = idx >> 3, slot = idx & 7;
                int srow = row < S_ ? row : S_ - 1;
                int sw = slot ^ (row & 7);
                __builtin_amdgcn_global_load_lds((AS1 void*)(kbase + (size_t)srow * 1024 + sw * 8),
                                                 (AS3 void*)(Ks + idx * 8), 16, 0, 0);
            }
        }
        int d = tid & 63, sg = tid >> 6;
        const u16* vbase = kvo + (size_t)(n * S_) * 1024 + 512 + h * 64 + d;
        for (int s = sg; s < 104; s += 4) {
            u16 v = (s < S_) ? vbase[(size_t)s * 1024] : (u16)0;
            VT[d * 104 + s] = v;
        }
    }

    // acc + qbias -> Qs2[hw_loc][o_loc] bf16, swizzled per 64-wide head segment
    const float* qbn = qbias + n * C_;
#pragma unroll
    for (int mi = 0; mi < 4; mi++) {
        int o_loc = wm + mi * 16 + g * 4;
        float4 b4 = *(const float4*)(qbn + arow0 + o_loc);
#pragma unroll
        for (int ni = 0; ni < 4; ni++) {
            int hw_loc = wn + ni * 16 + l15;
            f32x4 v = acc[mi][ni];
            ushort4 wv;
            wv.x = f2bf(v[0] + b4.x); wv.y = f2bf(v[1] + b4.y);
            wv.z = f2bf(v[2] + b4.z); wv.w = f2bf(v[3] + b4.w);
            int dd = o_loc & 63, hsel = o_loc >> 6;
            int col = hsel * 64 + (((dd >> 3) ^ (hw_loc & 7)) << 3) + (dd & 7);
            *(ushort4*)&pool[hw_loc * 128 + col] = wv;
        }
    }
    for (int i = tid; i < 512; i += 256) {
        int rr = i >> 3, cp = i & 7;
        *(unsigned*)&Ps[rr * 104 + 80 + cp * 2] = 0u;
    }
    if (tid < 80) msk[tid] = (tid < S_) ? mask[n * S_ + tid] * 10000.f : 0.f;
    __syncthreads();   // Qs2 + head-0 Ks/VT + pad + msk all visible

    for (int hl = 0; hl < 2; hl++) {
        int h = h_base + hl;
        if (hl) {
            __syncthreads();   // head-0 Ks/VT reads done
            const u16* kbase = kvo + (size_t)(n * S_) * 1024 + h * 64;
#pragma unroll
            for (int pass = 0; pass < 3; pass++) {
                int idx = pass * 256 + tid;
                if (idx < 640) {
                    int row = idx >> 3, slot = idx & 7;
                    int srow = row < S_ ? row : S_ - 1;
                    int sw = slot ^ (row & 7);
                    __builtin_amdgcn_global_load_lds((AS1 void*)(kbase + (size_t)srow * 1024 + sw * 8),
                                                     (AS3 void*)(Ks + idx * 8), 16, 0, 0);
                }
            }
            int d = tid & 63, sg = tid >> 6;
            const u16* vbase = kvo + (size_t)(n * S_) * 1024 + 512 + h * 64 + d;
            for (int s = sg; s < 104; s += 4) {
                u16 v = (s < S_) ? vbase[(size_t)s * 1024] : (u16)0;
                VT[d * 104 + s] = v;
            }
            __syncthreads();   // head-1 Ks/VT ready
        }

        for (int qhalf = 0; qhalf < 2; qhalf++) {
            int qrl = qhalf * 64 + w * 16 + l15;   // local hw row 0..127
            bf16x8 qf[2];
#pragma unroll
            for (int kk = 0; kk < 2; kk++) {
                int s8 = kk * 4 + g;
                qf[kk] = *(const bf16x8*)(pool + qrl * 128 + hl * 64 + ((s8 ^ (qrl & 7)) << 3));
            }
            f32x4 sc[5];
#pragma unroll
            for (int kb = 0; kb < 5; kb++) {
                sc[kb] = 0.f;
#pragma unroll
                for (int kk = 0; kk < 2; kk++) {
                    int rr = kb * 16 + l15;
                    int s8 = kk * 4 + g;
                    bf16x8 kf = *(const bf16x8*)(Ks + rr * 64 + ((s8 ^ (rr & 7)) << 3));
                    sc[kb] = __builtin_amdgcn_mfma_f32_16x16x32_bf16(kf, qf[kk], sc[kb], 0, 0, 0);
                }
            }
            float sv[5][4];
            float mx = -3e38f;
#pragma unroll
            for (int kb = 0; kb < 5; kb++)
#pragma unroll
                for (int j = 0; j < 4; j++) {
                    int key = kb * 16 + g * 4 + j;
                    float s = sc[kb][j] * 0.125f - msk[key];
                    sv[kb][j] = s;
                    if (key < S_) mx = fmaxf(mx, s);
                }
            mx = fmaxf(mx, __shfl_xor(mx, 16));
            mx = fmaxf(mx, __shfl_xor(mx, 32));
            float sum = 0.f;
            float p[5][4];
#pragma unroll
            for (int kb = 0; kb < 5; kb++)
#pragma unroll
                for (int j = 0; j < 4; j++) {
                    int key = kb * 16 + g * 4 + j;
                    float pv = (key < S_) ? __expf(sv[kb][j] - mx) : 0.f;
                    p[kb][j] = pv;
                    sum += pv;
                }
            sum += __shfl_xor(sum, 16);
            sum += __shfl_xor(sum, 32);
            float inv = 1.f / sum;
            int prow = w * 16 + l15;   // wave-private Ps row
#pragma unroll
            for (int kb = 0; kb < 5; kb++) {
                unsigned lo = (unsigned)f2bf(p[kb][0] * inv) | ((unsigned)f2bf(p[kb][1] * inv) << 16);
                unsigned hi = (unsigned)f2bf(p[kb][2] * inv) | ((unsigned)f2bf(p[kb][3] * inv) << 16);
                int col = kb * 16 + g * 4;
                *(uint2*)&Ps[prow * 104 + col] = make_uint2(lo, hi);
            }
            f32x4 ya[4];
#pragma unroll
            for (int mf = 0; mf < 4; mf++) ya[mf] = 0.f;
#pragma unroll
            for (int kk = 0; kk < 3; kk++) {
                int s8 = kk * 4 + g;
                bf16x8 pf = *(const bf16x8*)(Ps + prow * 104 + s8 * 8);
#pragma unroll
                for (int mf = 0; mf < 4; mf++) {
                    bf16x8 vf = *(const bf16x8*)(VT + (mf * 16 + l15) * 104 + s8 * 8);
                    ya[mf] = __builtin_amdgcn_mfma_f32_16x16x32_bf16(vf, pf, ya[mf], 0, 0, 0);
                }
            }
            u16* yrow = yt + ((size_t)(n * HW_ + brow0 + qrl)) * C_ + h * 64;
#pragma unroll
            for (int mf = 0; mf < 4; mf++) {
                int d0 = mf * 16 + g * 4;
                ushort4 o;
                o.x = f2bf(ya[mf][0]); o.y = f2bf(ya[mf][1]);
                o.z = f2bf(ya[mf][2]); o.w = f2bf(ya[mf][3]);
                *(ushort4*)(yrow + d0) = o;
            }
        }
    }
}

// ---------------- OUT GEMM ----------------
__global__ __launch_bounds__(256) void gemm_out_mfma(const u16* __restrict__ owb,
                                                     const u16* __restrict__ yT,
                                                     const float* __restrict__ ob,
                                                     const float* __restrict__ inp,
                                                     float* __restrict__ outp) {
    __shared__ __align__(16) u16 As[128 * 64];
    __shared__ __align__(16) u16 Bs[128 * 64];
    int n = blockIdx.z;
    int arow0 = blockIdx.y * 128, brow0 = blockIdx.x * 128;
    f32x4 acc[4][4];
#pragma unroll
    for (int mi = 0; mi < 4; mi++)
#pragma unroll
        for (int ni = 0; ni < 4; ni++) acc[mi][ni] = 0.f;
    gemm_mainloop(owb, C_, arow0, yT + (size_t)n * HW_ * C_, C_, brow0, HW_ - 1, C_, acc, As, Bs);
    int lane = threadIdx.x & 63, wid = threadIdx.x >> 6;
    int wm = (wid >> 1) * 64, wn = (wid & 1) * 64;
    float* Co = outp + (size_t)n * C_ * HW_;
    const float* In = inp + (size_t)n * C_ * HW_;
#pragma unroll
    for (int mi = 0; mi < 4; mi++) {
        int row = arow0 + wm + mi * 16 + ((lane >> 4) << 2);
        float4 b4 = *(const float4*)(ob + row);
#pragma unroll
        for (int ni = 0; ni < 4; ni++) {
            int col = brow0 + wn + ni * 16 + (lane & 15);
            f32x4 v = acc[mi][ni];
            size_t i0 = (size_t)row * HW_ + col;
            Co[i0]            = v[0] + b4.x + In[i0];
            Co[i0 + HW_]      = v[1] + b4.y + In[i0 + HW_];
            Co[i0 + 2 * HW_]  = v[2] + b4.z + In[i0 + 2 * HW_];
            Co[i0 + 3 * HW_]  = v[3] + b4.w + In[i0 + 3 * HW_];
        }
    }
}

extern "C" void kernel_launch(void* const* d_in, const int* in_sizes, int n_in,
                              void* d_out, int out_size, void* d_ws, size_t ws_size,
                              hipStream_t stream) {
    const float* inp  = (const float*)d_in[0];
    const float* cond = (const float*)d_in[1];
    const float* enc  = (const float*)d_in[2];
    const float* mask = (const float*)d_in[3];
    const float* agw  = (const float*)d_in[4];
    const float* agb  = (const float*)d_in[5];
    const float* lnw  = (const float*)d_in[6];
    const float* lnb  = (const float*)d_in[7];
    const float* qw   = (const float*)d_in[8];
    const float* qb   = (const float*)d_in[9];
    const float* kvw  = (const float*)d_in[10];
    const float* kvb  = (const float*)d_in[11];
    const float* ow   = (const float*)d_in[12];
    const float* ob   = (const float*)d_in[13];
    float* ws  = (float*)d_ws;
    float* out = (float*)d_out;
    u16* wsu = (u16*)((char*)d_ws + WSU_BYTE);
    float* ssf = (float*)(wsu + U_YT);     // 16x1024 fp32, consumed before mega3 writes yT

    // mega1: gemv_ss(64) | stats(256) | cvt3(1280) | ln(1232) = 2832 blocks
    mega1_kernel<<<dim3(2832), 256, 0, stream>>>(inp, ws + WS_PSTAT,
                                                 qw, ow, kvw, wsu + U_QW, wsu + U_OW, wsu + U_KVW,
                                                 enc, lnw, lnb, wsu + U_EB,
                                                 cond, agw, agb, ssf);
    // mega2: KV GEMM(80) | qbias(32) | xT(2048) = 2160 blocks
    mega2_kernel<<<dim3(2160), 256, 0, stream>>>(inp, ssf, ws + WS_PSTAT,
                                                 wsu + U_XT, qw, qb, ws + WS_QBIAS,
                                                 wsu + U_KVW, wsu + U_EB, kvb, wsu + U_KVB);
    // mega3: fused Q-GEMM + attention (512 blocks)
    mega3_kernel<<<dim3(512), 256, 0, stream>>>(wsu + U_QW, wsu + U_XT, ws + WS_QBIAS,
                                                wsu + U_KVB, mask, wsu + U_YT);

    gemm_out_mfma<<<dim3(HW_ / 128, C_ / 128, N_), 256, 0, stream>>>(
        wsu + U_OW, wsu + U_YT, ob, inp, out);
}